// Round 5
// baseline (258.367 us; speedup 1.0000x reference)
//
#include <hip/hip_runtime.h>
#include <hip/hip_bf16.h>
#include <cstdint>

typedef unsigned short u16;
typedef __attribute__((ext_vector_type(4))) float f32x4;
typedef __attribute__((ext_vector_type(8))) short s16x8;
typedef __attribute__((ext_vector_type(4))) unsigned int u32x4;

#define B_    2
#define LQ_   2048
#define LKV_  2048
#define H_    16
// softmax scale folded into Q at GEMM epilogue: 0.125 * log2(e)
#define QSCALE_ 0.18033688011112042f

__device__ __forceinline__ u16 f2b(float f) {
  union { float f; unsigned int u; } v; v.f = f;
  unsigned int r = v.u + 0x7fffu + ((v.u >> 16) & 1u);
  return (u16)(r >> 16);
}

__device__ __forceinline__ unsigned cvtpk(float lo, float hi) {
  unsigned r;
  asm("v_cvt_pk_bf16_f32 %0, %1, %2" : "=v"(r) : "v"(lo), "v"(hi));
  return r;
}

// ---------------- elementwise cast fp32 -> bf16 ----------------
__global__ void cast_bf16(const float* __restrict__ in, u16* __restrict__ out, int n) {
  int i = (blockIdx.x * 256 + threadIdx.x) * 4;
  if (i >= n) return;
  float4 v = *reinterpret_cast<const float4*>(in + i);
  ushort4 r;
  r.x = f2b(v.x); r.y = f2b(v.y); r.z = f2b(v.z); r.w = f2b(v.w);
  *reinterpret_cast<ushort4*>(out + i) = r;
}

// ---------------- zero fill (f32x4 per thread, exact) ----------------
__global__ void zero_f32(float* __restrict__ p) {
  int i = (blockIdx.x * 256 + threadIdx.x) * 4;
  *reinterpret_cast<float4*>(p + i) = (float4){0.f, 0.f, 0.f, 0.f};
}

// ---------------- transpose + cast: W[K][N] f32 -> WT[N][K] bf16 ----------------
__global__ void transpose_cast(const float* __restrict__ W, u16* __restrict__ WT, int K, int N) {
  __shared__ u16 tile[64][65];
  const int t = threadIdx.x;
  const int n0 = blockIdx.x * 64, k0 = blockIdx.y * 64;
#pragma unroll
  for (int p = 0; p < 4; ++p) {
    int r = (t >> 4) + p * 16;
    int c = (t & 15) * 4;
    float4 v = *reinterpret_cast<const float4*>(W + (size_t)(k0 + r) * N + n0 + c);
    tile[r][c + 0] = f2b(v.x);
    tile[r][c + 1] = f2b(v.y);
    tile[r][c + 2] = f2b(v.z);
    tile[r][c + 3] = f2b(v.w);
  }
  __syncthreads();
#pragma unroll
  for (int p = 0; p < 4; ++p) {
    int nr = (t >> 4) + p * 16;
    int kc = (t & 15) * 4;
    ushort4 o;
    o.x = tile[kc + 0][nr];
    o.y = tile[kc + 1][nr];
    o.z = tile[kc + 2][nr];
    o.w = tile[kc + 3][nr];
    *reinterpret_cast<ushort4*>(WT + (size_t)(n0 + nr) * K + k0 + kc) = o;
  }
}

// ---------------- GEMM: C[M,N] = A[M,K] * BT[N,K]^T, BM=128 BN=64 BK=32 ----------------
// OM==1: fp32 out + bias (proj)
// OM==2: KV split: cols<1024 -> K to Cb [M,1024]; cols>=1024 -> V transposed to VTp[bh][d][kv]
// OM==3: bf16 out scaled by QSCALE_ (Q projection)
template <int OM>
__global__ __launch_bounds__(256, 4)
void gemm_bt(const u16* __restrict__ A, const u16* __restrict__ BT,
             u16* __restrict__ Cb, float* __restrict__ Cf,
             const float* __restrict__ bias, u16* __restrict__ VTp,
             int M, int N, int K) {
  __shared__ u16 sA[128 * 32];
  __shared__ u16 sB[64 * 32];
  const int tid = threadIdx.x;
  const int w = tid >> 6, lane = tid & 63;
  const int l16 = lane & 15, lk = lane >> 4;
  const int m0 = blockIdx.x * 128, n0 = blockIdx.y * 64;
  const int wm = w >> 1, wn = w & 1;

  f32x4 acc[4][2];
#pragma unroll
  for (int i = 0; i < 4; ++i)
#pragma unroll
    for (int j = 0; j < 2; ++j)
      acc[i][j] = (f32x4){0.f, 0.f, 0.f, 0.f};

  const u16* ga0 = A  + (size_t)(m0 + (tid >> 2)) * K + (tid & 3) * 8;
  const u16* ga1 = ga0 + (size_t)64 * K;
  const u16* gb0 = BT + (size_t)(n0 + (tid >> 2)) * K + (tid & 3) * 8;
  u16* la0 = sA + tid * 8;
  u16* la1 = la0 + 64 * 32;
  u16* lb0 = sB + tid * 8;

  for (int k0 = 0; k0 < K; k0 += 32) {
    __builtin_amdgcn_global_load_lds((const __attribute__((address_space(1))) void*)ga0,
                                     (__attribute__((address_space(3))) void*)la0, 16, 0, 0);
    __builtin_amdgcn_global_load_lds((const __attribute__((address_space(1))) void*)ga1,
                                     (__attribute__((address_space(3))) void*)la1, 16, 0, 0);
    __builtin_amdgcn_global_load_lds((const __attribute__((address_space(1))) void*)gb0,
                                     (__attribute__((address_space(3))) void*)lb0, 16, 0, 0);
    ga0 += 32; ga1 += 32; gb0 += 32;
    __syncthreads();

    s16x8 af[4], bf[2];
#pragma unroll
    for (int mt = 0; mt < 4; ++mt)
      af[mt] = *reinterpret_cast<const s16x8*>(sA + (wm * 64 + mt * 16 + l16) * 32 + lk * 8);
#pragma unroll
    for (int nt = 0; nt < 2; ++nt)
      bf[nt] = *reinterpret_cast<const s16x8*>(sB + (wn * 32 + nt * 16 + l16) * 32 + lk * 8);
#pragma unroll
    for (int mt = 0; mt < 4; ++mt)
#pragma unroll
      for (int nt = 0; nt < 2; ++nt)
        acc[mt][nt] = __builtin_amdgcn_mfma_f32_16x16x32_bf16(af[mt], bf[nt], acc[mt][nt], 0, 0, 0);
    __syncthreads();
  }

#pragma unroll
  for (int mt = 0; mt < 4; ++mt) {
#pragma unroll
    for (int nt = 0; nt < 2; ++nt) {
      const int col = n0 + wn * 32 + nt * 16 + l16;
      const int row0 = m0 + wm * 64 + mt * 16 + lk * 4;
      if (OM == 2 && col >= 1024) {
        int b = row0 >> 11, kv = row0 & 2047;
        int h = (col >> 6) & 15, d = col & 63;
        ushort4 o;
        o.x = f2b(acc[mt][nt][0]); o.y = f2b(acc[mt][nt][1]);
        o.z = f2b(acc[mt][nt][2]); o.w = f2b(acc[mt][nt][3]);
        *reinterpret_cast<ushort4*>(VTp + (((size_t)(b * 16 + h) * 64 + d) * 2048 + kv)) = o;
      } else {
#pragma unroll
        for (int j = 0; j < 4; ++j) {
          int row = row0 + j;
          if (OM == 3)      Cb[(size_t)row * N + col] = f2b(acc[mt][nt][j] * QSCALE_);
          else if (OM == 2) Cb[(size_t)row * 1024 + col] = f2b(acc[mt][nt][j]);
          else              Cf[(size_t)row * N + col] = acc[mt][nt][j] + bias[col];
        }
      }
    }
  }
}

// ---------------- flash attention v5: KV-split x2, 32q/wave, no-max exp2 ----------------
// grid 1024 = (bh 32) x (half 2) x (qt 16); 4 waves x 32 q-rows = 128 q/block.
// Q pre-scaled by 0.125*log2e; |S_log2| <~ 9 so exp2 needs no max subtraction.
// S^T = mfma(K_perm, Q^T); P stays in registers; O^T = mfma(VT, P^T);
// denominator via ones-row MFMA. Unnormalized (O,d) atomicAdd'd to f32 workspace.
__global__ __launch_bounds__(256, 4)
void flash_attn(const u16* __restrict__ Kq, const u16* __restrict__ Qb,
                const u16* __restrict__ VT, float* __restrict__ Oat,
                float* __restrict__ Dat) {
  __shared__ u16 sK[2][4096];   // [64 kv-rows][128B], chunk c holds global chunk c^(row&7)
  __shared__ u16 sV[2][4096];   // [64 d-rows][128B], same swizzle

  const int tid = threadIdx.x;
  const int w = tid >> 6, l = tid & 63;
  const int l16 = l & 15, lk = l >> 4;

  // bijective XCD swizzle: 1024 blocks = 8 x 128
  const int bid = blockIdx.x;
  const int wg = ((bid & 7) << 7) | (bid >> 3);
  const int qt = wg & 15, half = (wg >> 4) & 1, bh = wg >> 5;
  const int b = bh >> 4, h = bh & 15;
  const int qrow0 = qt * 128 + w * 32;
  const int kv0 = half * 1024;

  // Q B-fragments (col=q=l16, k=dk), 2 groups of 16 q
  const u16* qp = Qb + ((size_t)(b * LQ_ + qrow0 + l16)) * 1024 + h * 64;
  s16x8 qf[2][2];
#pragma unroll
  for (int g = 0; g < 2; ++g)
#pragma unroll
    for (int ks = 0; ks < 2; ++ks)
      qf[g][ks] = *reinterpret_cast<const s16x8*>(qp + g * 16 * 1024 + ks * 32 + lk * 8);

  f32x4 Oacc[2][4], Osum[2];
#pragma unroll
  for (int g = 0; g < 2; ++g) {
    Osum[g] = (f32x4){0.f, 0.f, 0.f, 0.f};
#pragma unroll
    for (int dt = 0; dt < 4; ++dt) Oacc[g][dt] = (f32x4){0.f, 0.f, 0.f, 0.f};
  }

  const u16* Kg = Kq + ((size_t)(b * LKV_ + kv0)) * 1024 + h * 64;  // K rows stride 1024
  const u16* Vg = VT + ((size_t)bh * 64) * 2048 + kv0;              // VT rows (d) stride 2048

  // ones A-fragment (bf16 1.0) for the denominator MFMA
  s16x8 ones;
#pragma unroll
  for (int i = 0; i < 8; ++i) ones[i] = (short)0x3F80;

  // QK A-frag row constants
  const int r0 = ((l16 >> 2) << 3) + (l16 & 3);
  const int xpar = (l16 >> 2) & 1;
  const int swv = (l16 & 7) << 4;

  // staging: 256 threads, 2 rounds each of K and V (16B per thread per round)
  const int srow = tid >> 3;
  const int scol = (tid & 7) ^ (srow & 7);

  auto stage = [&](int jt, int bb) {
#pragma unroll
    for (int i = 0; i < 2; ++i) {
      int row = srow + i * 32;
      __builtin_amdgcn_global_load_lds(
          (const __attribute__((address_space(1))) void*)(Kg + ((size_t)(jt * 64 + row)) * 1024 + scol * 8),
          (__attribute__((address_space(3))) void*)(sK[bb] + w * 512 + i * 2048), 16, 0, 0);
      __builtin_amdgcn_global_load_lds(
          (const __attribute__((address_space(1))) void*)(Vg + ((size_t)row) * 2048 + jt * 64 + scol * 8),
          (__attribute__((address_space(3))) void*)(sV[bb] + w * 512 + i * 2048), 16, 0, 0);
    }
  };

  stage(0, 0);
  __syncthreads();

  int cur = 0;
  for (int jt = 0; jt < 16; ++jt) {
    if (jt < 15) stage(jt + 1, cur ^ 1);
    const char* kb = (const char*)sK[cur];
    const char* vb = (const char*)sV[cur];

    // ---- S^T = K_perm . Q^T (exp2 domain, no max) ----
    f32x4 sacc[2][4];
#pragma unroll
    for (int g = 0; g < 2; ++g)
#pragma unroll
      for (int ct = 0; ct < 4; ++ct) sacc[g][ct] = (f32x4){0.f, 0.f, 0.f, 0.f};

    __builtin_amdgcn_s_setprio(1);
#pragma unroll
    for (int ct = 0; ct < 4; ++ct) {
      const int R = r0 + (((ct & 1) ^ xpar) << 2) + ((ct >> 1) << 5);
      const char* rp = kb + R * 128;
      const int sw = (R & 7) << 4;
      s16x8 ka0 = *reinterpret_cast<const s16x8*>(rp + ((lk * 16) ^ sw));
      s16x8 ka1 = *reinterpret_cast<const s16x8*>(rp + ((64 + lk * 16) ^ sw));
      sacc[0][ct] = __builtin_amdgcn_mfma_f32_16x16x32_bf16(ka0, qf[0][0], sacc[0][ct], 0, 0, 0);
      sacc[0][ct] = __builtin_amdgcn_mfma_f32_16x16x32_bf16(ka1, qf[0][1], sacc[0][ct], 0, 0, 0);
      sacc[1][ct] = __builtin_amdgcn_mfma_f32_16x16x32_bf16(ka0, qf[1][0], sacc[1][ct], 0, 0, 0);
      sacc[1][ct] = __builtin_amdgcn_mfma_f32_16x16x32_bf16(ka1, qf[1][1], sacc[1][ct], 0, 0, 0);
    }
    __builtin_amdgcn_s_setprio(0);

    // ---- P = exp2(S) in-register ----
#pragma unroll
    for (int g = 0; g < 2; ++g)
#pragma unroll
      for (int ct = 0; ct < 4; ++ct)
#pragma unroll
        for (int j = 0; j < 4; ++j)
          sacc[g][ct][j] = exp2f(sacc[g][ct][j]);

    // ---- O^T += VT . P^T ; denominator += ones . P^T ----
    const bool sel = (lk & 1) != 0;
#pragma unroll
    for (int f = 0; f < 2; ++f) {
      s16x8 pf[2];
#pragma unroll
      for (int g = 0; g < 2; ++g) {
        f32x4 pA = sel ? sacc[g][2 * f + 1] : sacc[g][2 * f];
        f32x4 pB = sel ? sacc[g][2 * f] : sacc[g][2 * f + 1];
        union { unsigned u[4]; s16x8 v; } pk;
        pk.u[0] = cvtpk(pA[0], pA[1]);
        pk.u[1] = cvtpk(pA[2], pA[3]);
        pk.u[2] = cvtpk(pB[0], pB[1]);
        pk.u[3] = cvtpk(pB[2], pB[3]);
        pf[g] = pk.v;
      }
      __builtin_amdgcn_s_setprio(1);
#pragma unroll
      for (int dt = 0; dt < 4; ++dt) {
        const char* vrp = vb + (dt * 16 + l16) * 128;
        s16x8 va = *reinterpret_cast<const s16x8*>(vrp + ((f * 64 + lk * 16) ^ swv));
        Oacc[0][dt] = __builtin_amdgcn_mfma_f32_16x16x32_bf16(va, pf[0], Oacc[0][dt], 0, 0, 0);
        Oacc[1][dt] = __builtin_amdgcn_mfma_f32_16x16x32_bf16(va, pf[1], Oacc[1][dt], 0, 0, 0);
      }
      Osum[0] = __builtin_amdgcn_mfma_f32_16x16x32_bf16(ones, pf[0], Osum[0], 0, 0, 0);
      Osum[1] = __builtin_amdgcn_mfma_f32_16x16x32_bf16(ones, pf[1], Osum[1], 0, 0, 0);
      __builtin_amdgcn_s_setprio(0);
    }
    __syncthreads();
    cur ^= 1;
  }

  // ---- epilogue: atomic-accumulate unnormalized partials ----
#pragma unroll
  for (int g = 0; g < 2; ++g) {
    const size_t row = (size_t)bh * 2048 + qrow0 + g * 16 + l16;
    float* od = Oat + row * 64 + lk * 4;
#pragma unroll
    for (int dt = 0; dt < 4; ++dt) {
#pragma unroll
      for (int j = 0; j < 4; ++j)
        atomicAdd(od + dt * 16 + j, Oacc[g][dt][j]);
    }
    if (lk == 0) atomicAdd(Dat + row, Osum[g][0]);
  }
}

// ---------------- normalize: Rb[b,q][h*64+d] = Oat/Dat ----------------
__global__ void attn_norm(const float* __restrict__ Oat, const float* __restrict__ Dat,
                          u16* __restrict__ Rb) {
  const int t = threadIdx.x;
  const int row = blockIdx.x * 16 + (t >> 4);   // 0..65535 = bh*2048 + q
  const int d0 = (t & 15) * 4;
  const int bh = row >> 11, q = row & 2047;
  const int b = bh >> 4, h = bh & 15;
  float inv = 1.f / Dat[row];
  float4 v = *reinterpret_cast<const float4*>(Oat + (size_t)row * 64 + d0);
  ushort4 o;
  o.x = f2b(v.x * inv); o.y = f2b(v.y * inv);
  o.z = f2b(v.z * inv); o.w = f2b(v.w * inv);
  *reinterpret_cast<ushort4*>(Rb + ((size_t)(b * 2048 + q)) * 1024 + h * 64 + d0) = o;
}

// ---------------- launch ----------------
extern "C" void kernel_launch(void* const* d_in, const int* in_sizes, int n_in,
                              void* d_out, int out_size, void* d_ws, size_t ws_size,
                              hipStream_t stream) {
  const float* x   = (const float*)d_in[0];
  const float* y   = (const float*)d_in[1];
  const float* Wq  = (const float*)d_in[2];
  const float* Wkv = (const float*)d_in[3];
  const float* Wp  = (const float*)d_in[4];
  const float* bp  = (const float*)d_in[5];
  float* out = (float*)d_out;

  u16* p = (u16*)d_ws;
  u16* xb   = p; p += (size_t)4096 * 1024;
  u16* yb   = p; p += (size_t)4096 * 768;
  u16* WqT  = p; p += (size_t)1024 * 1024;
  u16* WkvT = p; p += (size_t)2048 * 768;
  u16* WpT  = p; p += (size_t)1024 * 1024;
  u16* Qb   = p; p += (size_t)4096 * 1024;
  u16* Kbf  = p; p += (size_t)4096 * 1024;   // K compact [b*2048+kv][h*64+d]
  u16* VTb  = p; p += (size_t)4096 * 1024;   // [32][64][2048]
  u16* Rb   = p; p += (size_t)4096 * 1024;

  // f32 partial buffers overlay dead xb..WkvT region (17.04 MB < 19.9 MB)
  float* Oat = (float*)d_ws;                 // [65536][64]
  float* Dat = Oat + (size_t)65536 * 64;     // [65536]

  cast_bf16<<<4096, 256, 0, stream>>>(x, xb, 4096 * 1024);
  cast_bf16<<<3072, 256, 0, stream>>>(y, yb, 4096 * 768);
  transpose_cast<<<dim3(16, 16), 256, 0, stream>>>(Wq, WqT, 1024, 1024);
  transpose_cast<<<dim3(32, 12), 256, 0, stream>>>(Wkv, WkvT, 768, 2048);
  transpose_cast<<<dim3(16, 16), 256, 0, stream>>>(Wp, WpT, 1024, 1024);

  // Q = (x @ Wq) * 0.125*log2e : bf16 [4096,1024]
  gemm_bt<3><<<dim3(32, 16), 256, 0, stream>>>(xb, WqT, Qb, nullptr, nullptr, nullptr, 4096, 1024, 1024);
  // KV = y @ Wkv : K -> Kbf, V -> VTb (transposed in epilogue)
  gemm_bt<2><<<dim3(32, 32), 256, 0, stream>>>(yb, WkvT, Kbf, nullptr, nullptr, VTb, 4096, 2048, 768);
  // zero partials (xb/yb/WqT/WkvT now dead), then attention
  zero_f32<<<4160, 256, 0, stream>>>(Oat);
  flash_attn<<<1024, 256, 0, stream>>>(Kbf, Qb, VTb, Oat, Dat);
  attn_norm<<<4096, 256, 0, stream>>>(Oat, Dat, Rb);
  // out = Rb @ Wproj + bias : fp32 [4096,1024]
  gemm_bt<1><<<dim3(32, 16), 256, 0, stream>>>(Rb, WpT, nullptr, out, bp, nullptr, 4096, 1024, 1024);
}

// Round 6
// 141.654 us; speedup vs baseline: 1.8239x; 1.8239x over previous
//
#include <hip/hip_runtime.h>
#include <hip/hip_bf16.h>
#include <cstdint>

typedef unsigned short u16;
typedef __attribute__((ext_vector_type(4))) float f32x4;
typedef __attribute__((ext_vector_type(8))) short s16x8;
typedef __attribute__((ext_vector_type(4))) unsigned int u32x4;

#define B_    2
#define LQ_   2048
#define LKV_  2048
#define H_    16
// softmax scale folded into Q at GEMM epilogue: 0.125 * log2(e)
#define QSCALE_ 0.18033688011112042f

__device__ __forceinline__ u16 f2b(float f) {
  union { float f; unsigned int u; } v; v.f = f;
  unsigned int r = v.u + 0x7fffu + ((v.u >> 16) & 1u);
  return (u16)(r >> 16);
}

__device__ __forceinline__ unsigned cvtpk(float lo, float hi) {
  unsigned r;
  asm("v_cvt_pk_bf16_f32 %0, %1, %2" : "=v"(r) : "v"(lo), "v"(hi));
  return r;
}

// ---------------- elementwise cast fp32 -> bf16 ----------------
__global__ void cast_bf16(const float* __restrict__ in, u16* __restrict__ out, int n) {
  int i = (blockIdx.x * 256 + threadIdx.x) * 4;
  if (i >= n) return;
  float4 v = *reinterpret_cast<const float4*>(in + i);
  ushort4 r;
  r.x = f2b(v.x); r.y = f2b(v.y); r.z = f2b(v.z); r.w = f2b(v.w);
  *reinterpret_cast<ushort4*>(out + i) = r;
}

// ---------------- transpose + cast: W[K][N] f32 -> WT[N][K] bf16 ----------------
__global__ void transpose_cast(const float* __restrict__ W, u16* __restrict__ WT, int K, int N) {
  __shared__ u16 tile[64][65];
  const int t = threadIdx.x;
  const int n0 = blockIdx.x * 64, k0 = blockIdx.y * 64;
#pragma unroll
  for (int p = 0; p < 4; ++p) {
    int r = (t >> 4) + p * 16;
    int c = (t & 15) * 4;
    float4 v = *reinterpret_cast<const float4*>(W + (size_t)(k0 + r) * N + n0 + c);
    tile[r][c + 0] = f2b(v.x);
    tile[r][c + 1] = f2b(v.y);
    tile[r][c + 2] = f2b(v.z);
    tile[r][c + 3] = f2b(v.w);
  }
  __syncthreads();
#pragma unroll
  for (int p = 0; p < 4; ++p) {
    int nr = (t >> 4) + p * 16;
    int kc = (t & 15) * 4;
    ushort4 o;
    o.x = tile[kc + 0][nr];
    o.y = tile[kc + 1][nr];
    o.z = tile[kc + 2][nr];
    o.w = tile[kc + 3][nr];
    *reinterpret_cast<ushort4*>(WT + (size_t)(n0 + nr) * K + k0 + kc) = o;
  }
}

// ---------------- GEMM: C[M,N] = A[M,K] * BT[N,K]^T, BM=128 BN=64 BK=32 ----------------
// OM==1: fp32 out + bias (proj)
// OM==2: KV split: cols<1024 -> K to Cb [M,1024]; cols>=1024 -> V transposed to VTp[bh][d][kv]
// OM==3: bf16 out scaled by QSCALE_ (Q projection)
template <int OM>
__global__ __launch_bounds__(256, 4)
void gemm_bt(const u16* __restrict__ A, const u16* __restrict__ BT,
             u16* __restrict__ Cb, float* __restrict__ Cf,
             const float* __restrict__ bias, u16* __restrict__ VTp,
             int M, int N, int K) {
  __shared__ u16 sA[128 * 32];
  __shared__ u16 sB[64 * 32];
  const int tid = threadIdx.x;
  const int w = tid >> 6, lane = tid & 63;
  const int l16 = lane & 15, lk = lane >> 4;
  const int m0 = blockIdx.x * 128, n0 = blockIdx.y * 64;
  const int wm = w >> 1, wn = w & 1;

  f32x4 acc[4][2];
#pragma unroll
  for (int i = 0; i < 4; ++i)
#pragma unroll
    for (int j = 0; j < 2; ++j)
      acc[i][j] = (f32x4){0.f, 0.f, 0.f, 0.f};

  const u16* ga0 = A  + (size_t)(m0 + (tid >> 2)) * K + (tid & 3) * 8;
  const u16* ga1 = ga0 + (size_t)64 * K;
  const u16* gb0 = BT + (size_t)(n0 + (tid >> 2)) * K + (tid & 3) * 8;
  u16* la0 = sA + tid * 8;
  u16* la1 = la0 + 64 * 32;
  u16* lb0 = sB + tid * 8;

  for (int k0 = 0; k0 < K; k0 += 32) {
    __builtin_amdgcn_global_load_lds((const __attribute__((address_space(1))) void*)ga0,
                                     (__attribute__((address_space(3))) void*)la0, 16, 0, 0);
    __builtin_amdgcn_global_load_lds((const __attribute__((address_space(1))) void*)ga1,
                                     (__attribute__((address_space(3))) void*)la1, 16, 0, 0);
    __builtin_amdgcn_global_load_lds((const __attribute__((address_space(1))) void*)gb0,
                                     (__attribute__((address_space(3))) void*)lb0, 16, 0, 0);
    ga0 += 32; ga1 += 32; gb0 += 32;
    __syncthreads();

    s16x8 af[4], bf[2];
#pragma unroll
    for (int mt = 0; mt < 4; ++mt)
      af[mt] = *reinterpret_cast<const s16x8*>(sA + (wm * 64 + mt * 16 + l16) * 32 + lk * 8);
#pragma unroll
    for (int nt = 0; nt < 2; ++nt)
      bf[nt] = *reinterpret_cast<const s16x8*>(sB + (wn * 32 + nt * 16 + l16) * 32 + lk * 8);
#pragma unroll
    for (int mt = 0; mt < 4; ++mt)
#pragma unroll
      for (int nt = 0; nt < 2; ++nt)
        acc[mt][nt] = __builtin_amdgcn_mfma_f32_16x16x32_bf16(af[mt], bf[nt], acc[mt][nt], 0, 0, 0);
    __syncthreads();
  }

#pragma unroll
  for (int mt = 0; mt < 4; ++mt) {
#pragma unroll
    for (int nt = 0; nt < 2; ++nt) {
      const int col = n0 + wn * 32 + nt * 16 + l16;
      const int row0 = m0 + wm * 64 + mt * 16 + lk * 4;
      if (OM == 2 && col >= 1024) {
        int b = row0 >> 11, kv = row0 & 2047;
        int h = (col >> 6) & 15, d = col & 63;
        ushort4 o;
        o.x = f2b(acc[mt][nt][0]); o.y = f2b(acc[mt][nt][1]);
        o.z = f2b(acc[mt][nt][2]); o.w = f2b(acc[mt][nt][3]);
        *reinterpret_cast<ushort4*>(VTp + (((size_t)(b * 16 + h) * 64 + d) * 2048 + kv)) = o;
      } else {
#pragma unroll
        for (int j = 0; j < 4; ++j) {
          int row = row0 + j;
          if (OM == 3)      Cb[(size_t)row * N + col] = f2b(acc[mt][nt][j] * QSCALE_);
          else if (OM == 2) Cb[(size_t)row * 1024 + col] = f2b(acc[mt][nt][j]);
          else              Cf[(size_t)row * N + col] = acc[mt][nt][j] + bias[col];
        }
      }
    }
  }
}

// ---------------- flash attention v6: KV-split x2 merged in LDS ----------------
// 512 threads = 8 waves: waves 0-3 -> KV half 0, waves 4-7 -> half 1; same 128 q.
// grid 512 = (bh 32) x (qt 16); 32 q/wave; 2 blocks/CU, 4 waves/SIMD.
// Q pre-scaled by 0.125*log2e; |S_log2| <~ 9 so exp2 needs no max subtraction.
// S^T = mfma(K_perm, Q^T); P stays in registers; O^T = mfma(VT, P^T);
// denominator via ones-row MFMA. Halves merged through LDS, Rb written directly.
__global__ __launch_bounds__(512, 4)
void flash_attn(const u16* __restrict__ Kq, const u16* __restrict__ Qb,
                const u16* __restrict__ VT, u16* __restrict__ Rb) {
  // per half (32 KB): K dbuf 2x8KB, V dbuf 2x8KB. total 64 KB.
  __shared__ char smem[65536];
  __shared__ float dmerge[512 * 2];

  const int tid = threadIdx.x;
  const int w = tid >> 6, l = tid & 63;
  const int l16 = l & 15, lk = l >> 4;
  const int half = w >> 2, w4 = w & 3;

  // bijective XCD swizzle: 512 blocks = 8 x 64 -> 4 bh per XCD L2
  const int bid = blockIdx.x;
  const int wg = ((bid & 7) << 6) | (bid >> 3);
  const int qt = wg & 15, bh = wg >> 4;
  const int b = bh >> 4, h = bh & 15;
  const int qrow0 = qt * 128 + w4 * 32;

  // Q B-fragments (col=q=l16, k=dk), 2 groups of 16 q
  const u16* qp = Qb + ((size_t)(b * LQ_ + qrow0 + l16)) * 1024 + h * 64;
  s16x8 qf[2][2];
#pragma unroll
  for (int g = 0; g < 2; ++g)
#pragma unroll
    for (int ks = 0; ks < 2; ++ks)
      qf[g][ks] = *reinterpret_cast<const s16x8*>(qp + g * 16 * 1024 + ks * 32 + lk * 8);

  f32x4 Oacc[2][4], Osum[2];
#pragma unroll
  for (int g = 0; g < 2; ++g) {
    Osum[g] = (f32x4){0.f, 0.f, 0.f, 0.f};
#pragma unroll
    for (int dt = 0; dt < 4; ++dt) Oacc[g][dt] = (f32x4){0.f, 0.f, 0.f, 0.f};
  }

  // this wave's half: kv in [half*1024, half*1024+1024)
  const u16* Kg = Kq + ((size_t)(b * LKV_ + half * 1024)) * 1024 + h * 64; // K rows stride 1024
  const u16* Vg = VT + ((size_t)bh * 64) * 2048 + half * 1024;            // VT rows (d) stride 2048
  char* Kl = smem + half * 32768;            // + cur*8192
  char* Vl = smem + half * 32768 + 16384;    // + cur*8192

  // ones A-fragment (bf16 1.0) for the denominator MFMA
  s16x8 ones;
#pragma unroll
  for (int i = 0; i < 8; ++i) ones[i] = (short)0x3F80;

  // QK A-frag row constants
  const int r0 = ((l16 >> 2) << 3) + (l16 & 3);
  const int xpar = (l16 >> 2) & 1;
  const int swv = (l16 & 7) << 4;

  // staging: each 256-thread group stages its half; 2 rounds each of K and V
  const int srow = (tid & 255) >> 3;               // 0..31
  const int scol = (tid & 7) ^ (srow & 7);         // pre-swizzled source chunk

  auto stage = [&](int jt, int bb) {
#pragma unroll
    for (int i = 0; i < 2; ++i) {
      int row = srow + i * 32;
      __builtin_amdgcn_global_load_lds(
          (const __attribute__((address_space(1))) void*)(Kg + ((size_t)(jt * 64 + row)) * 1024 + scol * 8),
          (__attribute__((address_space(3))) void*)(Kl + bb * 8192 + w4 * 1024 + i * 4096), 16, 0, 0);
      __builtin_amdgcn_global_load_lds(
          (const __attribute__((address_space(1))) void*)(Vg + ((size_t)row) * 2048 + jt * 64 + scol * 8),
          (__attribute__((address_space(3))) void*)(Vl + bb * 8192 + w4 * 1024 + i * 4096), 16, 0, 0);
    }
  };

  stage(0, 0);
  __syncthreads();

  int cur = 0;
  for (int jt = 0; jt < 16; ++jt) {
    if (jt < 15) stage(jt + 1, cur ^ 1);
    const char* kb = Kl + cur * 8192;
    const char* vb = Vl + cur * 8192;

    // ---- S^T = K_perm . Q^T (exp2 domain, no max) ----
    f32x4 sacc[2][4];
#pragma unroll
    for (int g = 0; g < 2; ++g)
#pragma unroll
      for (int ct = 0; ct < 4; ++ct) sacc[g][ct] = (f32x4){0.f, 0.f, 0.f, 0.f};

    __builtin_amdgcn_s_setprio(1);
#pragma unroll
    for (int ct = 0; ct < 4; ++ct) {
      const int R = r0 + (((ct & 1) ^ xpar) << 2) + ((ct >> 1) << 5);
      const char* rp = kb + R * 128;
      const int sw = (R & 7) << 4;
      s16x8 ka0 = *reinterpret_cast<const s16x8*>(rp + ((lk * 16) ^ sw));
      s16x8 ka1 = *reinterpret_cast<const s16x8*>(rp + ((64 + lk * 16) ^ sw));
      sacc[0][ct] = __builtin_amdgcn_mfma_f32_16x16x32_bf16(ka0, qf[0][0], sacc[0][ct], 0, 0, 0);
      sacc[0][ct] = __builtin_amdgcn_mfma_f32_16x16x32_bf16(ka1, qf[0][1], sacc[0][ct], 0, 0, 0);
      sacc[1][ct] = __builtin_amdgcn_mfma_f32_16x16x32_bf16(ka0, qf[1][0], sacc[1][ct], 0, 0, 0);
      sacc[1][ct] = __builtin_amdgcn_mfma_f32_16x16x32_bf16(ka1, qf[1][1], sacc[1][ct], 0, 0, 0);
    }
    __builtin_amdgcn_s_setprio(0);

    // ---- P = exp2(S) in-register ----
#pragma unroll
    for (int g = 0; g < 2; ++g)
#pragma unroll
      for (int ct = 0; ct < 4; ++ct)
#pragma unroll
        for (int j = 0; j < 4; ++j)
          sacc[g][ct][j] = exp2f(sacc[g][ct][j]);

    // ---- O^T += VT . P^T ; denominator += ones . P^T ----
    const bool sel = (lk & 1) != 0;
#pragma unroll
    for (int f = 0; f < 2; ++f) {
      s16x8 pf[2];
#pragma unroll
      for (int g = 0; g < 2; ++g) {
        f32x4 pA = sel ? sacc[g][2 * f + 1] : sacc[g][2 * f];
        f32x4 pB = sel ? sacc[g][2 * f] : sacc[g][2 * f + 1];
        union { unsigned u[4]; s16x8 v; } pk;
        pk.u[0] = cvtpk(pA[0], pA[1]);
        pk.u[1] = cvtpk(pA[2], pA[3]);
        pk.u[2] = cvtpk(pB[0], pB[1]);
        pk.u[3] = cvtpk(pB[2], pB[3]);
        pf[g] = pk.v;
      }
      __builtin_amdgcn_s_setprio(1);
#pragma unroll
      for (int dt = 0; dt < 4; ++dt) {
        const char* vrp = vb + (dt * 16 + l16) * 128;
        s16x8 va = *reinterpret_cast<const s16x8*>(vrp + ((f * 64 + lk * 16) ^ swv));
        Oacc[0][dt] = __builtin_amdgcn_mfma_f32_16x16x32_bf16(va, pf[0], Oacc[0][dt], 0, 0, 0);
        Oacc[1][dt] = __builtin_amdgcn_mfma_f32_16x16x32_bf16(va, pf[1], Oacc[1][dt], 0, 0, 0);
      }
      Osum[0] = __builtin_amdgcn_mfma_f32_16x16x32_bf16(ones, pf[0], Osum[0], 0, 0, 0);
      Osum[1] = __builtin_amdgcn_mfma_f32_16x16x32_bf16(ones, pf[1], Osum[1], 0, 0, 0);
      __builtin_amdgcn_s_setprio(0);
    }
    __syncthreads();   // also covers: staging regions reusable for merge after loop
    cur ^= 1;
  }

  // ---- merge halves through LDS (half-0 staging region, now dead) ----
  if (w >= 4) {
    char* mb = smem + (((w - 4) * 64 + l) * 128);
#pragma unroll
    for (int g = 0; g < 2; ++g)
#pragma unroll
      for (int dt = 0; dt < 4; ++dt)
        *reinterpret_cast<f32x4*>(mb + (((g * 4 + dt) * 16) ^ ((l & 7) << 4))) = Oacc[g][dt];
    dmerge[((w - 4) * 64 + l) * 2 + 0] = Osum[0][0];
    dmerge[((w - 4) * 64 + l) * 2 + 1] = Osum[1][0];
  }
  __syncthreads();
  if (w < 4) {
    const char* mb = smem + ((w * 64 + l) * 128);
#pragma unroll
    for (int g = 0; g < 2; ++g) {
      float inv = 1.f / (Osum[g][0] + dmerge[(w * 64 + l) * 2 + g]);
      u16* op = Rb + ((size_t)(b * LQ_ + qrow0 + g * 16 + l16)) * 1024 + h * 64 + lk * 4;
#pragma unroll
      for (int dt = 0; dt < 4; ++dt) {
        f32x4 o2 = *reinterpret_cast<const f32x4*>(mb + (((g * 4 + dt) * 16) ^ ((l & 7) << 4)));
        f32x4 s = Oacc[g][dt] + o2;
        ushort4 o;
        o.x = f2b(s[0] * inv); o.y = f2b(s[1] * inv);
        o.z = f2b(s[2] * inv); o.w = f2b(s[3] * inv);
        *reinterpret_cast<ushort4*>(op + dt * 16) = o;
      }
    }
  }
}

// ---------------- launch ----------------
extern "C" void kernel_launch(void* const* d_in, const int* in_sizes, int n_in,
                              void* d_out, int out_size, void* d_ws, size_t ws_size,
                              hipStream_t stream) {
  const float* x   = (const float*)d_in[0];
  const float* y   = (const float*)d_in[1];
  const float* Wq  = (const float*)d_in[2];
  const float* Wkv = (const float*)d_in[3];
  const float* Wp  = (const float*)d_in[4];
  const float* bp  = (const float*)d_in[5];
  float* out = (float*)d_out;

  u16* p = (u16*)d_ws;
  u16* xb   = p; p += (size_t)4096 * 1024;
  u16* yb   = p; p += (size_t)4096 * 768;
  u16* WqT  = p; p += (size_t)1024 * 1024;
  u16* WkvT = p; p += (size_t)2048 * 768;
  u16* WpT  = p; p += (size_t)1024 * 1024;
  u16* Qb   = p; p += (size_t)4096 * 1024;
  u16* Kbf  = p; p += (size_t)4096 * 1024;   // K compact [b*2048+kv][h*64+d]
  u16* VTb  = p; p += (size_t)4096 * 1024;   // [32][64][2048]
  u16* Rb   = p; p += (size_t)4096 * 1024;

  cast_bf16<<<4096, 256, 0, stream>>>(x, xb, 4096 * 1024);
  cast_bf16<<<3072, 256, 0, stream>>>(y, yb, 4096 * 768);
  transpose_cast<<<dim3(16, 16), 256, 0, stream>>>(Wq, WqT, 1024, 1024);
  transpose_cast<<<dim3(32, 12), 256, 0, stream>>>(Wkv, WkvT, 768, 2048);
  transpose_cast<<<dim3(16, 16), 256, 0, stream>>>(Wp, WpT, 1024, 1024);

  // Q = (x @ Wq) * 0.125*log2e : bf16 [4096,1024]
  gemm_bt<3><<<dim3(32, 16), 256, 0, stream>>>(xb, WqT, Qb, nullptr, nullptr, nullptr, 4096, 1024, 1024);
  // KV = y @ Wkv : K -> Kbf, V -> VTb (transposed in epilogue)
  gemm_bt<2><<<dim3(32, 32), 256, 0, stream>>>(yb, WkvT, Kbf, nullptr, nullptr, VTb, 4096, 2048, 768);
  // attention -> Rb [4096,1024] (halves merged in-block)
  flash_attn<<<512, 512, 0, stream>>>(Kbf, Qb, VTb, Rb);
  // out = Rb @ Wproj + bias : fp32 [4096,1024]
  gemm_bt<1><<<dim3(32, 16), 256, 0, stream>>>(Rb, WpT, nullptr, out, bp, nullptr, 4096, 1024, 1024);
}

// Round 8
// 125.214 us; speedup vs baseline: 2.0634x; 1.1313x over previous
//
#include <hip/hip_runtime.h>
#include <hip/hip_bf16.h>
#include <cstdint>

typedef unsigned short u16;
typedef __attribute__((ext_vector_type(4))) float f32x4;
typedef __attribute__((ext_vector_type(8))) short s16x8;
typedef __attribute__((ext_vector_type(4))) unsigned int u32x4;

#define B_    2
#define LQ_   2048
#define LKV_  2048
#define H_    16
// softmax scale folded into Q at GEMM epilogue: 0.125 * log2(e)
#define QSCALE_ 0.18033688011112042f

__device__ __forceinline__ u16 f2b(float f) {
  union { float f; unsigned int u; } v; v.f = f;
  unsigned int r = v.u + 0x7fffu + ((v.u >> 16) & 1u);
  return (u16)(r >> 16);
}

__device__ __forceinline__ unsigned cvtpk(float lo, float hi) {
  unsigned r;
  asm("v_cvt_pk_bf16_f32 %0, %1, %2" : "=v"(r) : "v"(lo), "v"(hi));
  return r;
}

// ---------------- fused cast fp32 -> bf16 (x then y by block range) ----------------
__global__ void cast2_bf16(const float* __restrict__ x, u16* __restrict__ xb,
                           const float* __restrict__ y, u16* __restrict__ yb) {
  const int bid = blockIdx.x;
  const float* in; u16* out; int i;
  if (bid < 4096) { in = x; out = xb; i = (bid * 256 + threadIdx.x) * 4; }
  else            { in = y; out = yb; i = ((bid - 4096) * 256 + threadIdx.x) * 4; }
  float4 v = *reinterpret_cast<const float4*>(in + i);
  ushort4 r;
  r.x = f2b(v.x); r.y = f2b(v.y); r.z = f2b(v.z); r.w = f2b(v.w);
  *reinterpret_cast<ushort4*>(out + i) = r;
}

// ---------------- fused transpose+cast of the three weights ----------------
__global__ void transpose_cast3(const float* __restrict__ Wq, u16* __restrict__ WqT,
                                const float* __restrict__ Wkv, u16* __restrict__ WkvT,
                                const float* __restrict__ Wp, u16* __restrict__ WpT) {
  __shared__ u16 tile[64][65];
  const int bid = blockIdx.x;
  const float* W; u16* WT; int K, N, bx, by;
  if (bid < 256)      { W = Wq;  WT = WqT;  K = 1024; N = 1024; bx = bid & 15;        by = bid >> 4; }
  else if (bid < 640) { W = Wkv; WT = WkvT; K = 768;  N = 2048; bx = (bid - 256) & 31; by = (bid - 256) >> 5; }
  else                { W = Wp;  WT = WpT;  K = 1024; N = 1024; bx = (bid - 640) & 15; by = (bid - 640) >> 4; }
  const int t = threadIdx.x;
  const int n0 = bx * 64, k0 = by * 64;
#pragma unroll
  for (int p = 0; p < 4; ++p) {
    int r = (t >> 4) + p * 16;
    int c = (t & 15) * 4;
    float4 v = *reinterpret_cast<const float4*>(W + (size_t)(k0 + r) * N + n0 + c);
    tile[r][c + 0] = f2b(v.x);
    tile[r][c + 1] = f2b(v.y);
    tile[r][c + 2] = f2b(v.z);
    tile[r][c + 3] = f2b(v.w);
  }
  __syncthreads();
#pragma unroll
  for (int p = 0; p < 4; ++p) {
    int nr = (t >> 4) + p * 16;
    int kc = (t & 15) * 4;
    ushort4 o;
    o.x = tile[kc + 0][nr];
    o.y = tile[kc + 1][nr];
    o.z = tile[kc + 2][nr];
    o.w = tile[kc + 3][nr];
    *reinterpret_cast<ushort4*>(WT + (size_t)(n0 + nr) * K + k0 + kc) = o;
  }
}

// ---------------- GEMM v2: split-K in block ----------------
// tile 128x64, 4 waves = 2(wm) x 2(ks); wave-tile 64x64 over K/2; BK=64.
// LDS rows are 128B -> XOR-16B swizzle (pre-swizzled global_load_lds source).
// K-halves merged through LDS (f32), ks==0 waves write C.
// OM==1: fp32 out + bias; OM==2: KV split (K compact / V transposed); OM==3: bf16 * QSCALE_.
template <int OM>
__global__ __launch_bounds__(256, 3)
void gemm_bt(const u16* __restrict__ A, const u16* __restrict__ BT,
             u16* __restrict__ Cb, float* __restrict__ Cf,
             const float* __restrict__ bias, u16* __restrict__ VTp,
             int M, int N, int K) {
  __shared__ char smem[49152];   // sA [2][128][64] @0 (32KB), sB [2][64][64] @32768 (16KB)
  const int tid = threadIdx.x;
  const int w = tid >> 6, lane = tid & 63;
  const int l16 = lane & 15, lk = lane >> 4;
  const int m0 = blockIdx.x * 128, n0 = blockIdx.y * 64;
  const int wm = w >> 1, ks = w & 1;
  const int K2 = K >> 1;

  f32x4 acc[4][4];
#pragma unroll
  for (int i = 0; i < 4; ++i)
#pragma unroll
    for (int j = 0; j < 4; ++j)
      acc[i][j] = (f32x4){0.f, 0.f, 0.f, 0.f};

  // staging: linear LDS dest, source granule pre-XORed with (row&7)
  const int kcs = (tid & 7) ^ ((tid >> 3) & 7);
  const u16* ga[8]; char* la[8];
  const u16* gb[4]; char* lb[4];
#pragma unroll
  for (int i = 0; i < 8; ++i) {
    int row = (i & 3) * 32 + (tid >> 3);
    ga[i] = A + (size_t)(m0 + row) * K + (i >> 2) * K2 + kcs * 8;
    la[i] = smem + (i >> 2) * 16384 + row * 128 + (tid & 7) * 16;
  }
#pragma unroll
  for (int i = 0; i < 4; ++i) {
    int row = (i & 1) * 32 + (tid >> 3);
    gb[i] = BT + (size_t)(n0 + row) * K + (i >> 1) * K2 + kcs * 8;
    lb[i] = smem + 32768 + (i >> 1) * 8192 + row * 128 + (tid & 7) * 16;
  }

  const char* sAb = smem + ks * 16384;
  const char* sBb = smem + 32768 + ks * 8192;
  const int swa = (l16 & 7) << 4;    // frag-row swizzle (row&7 == l16&7)

  for (int k0 = 0; k0 < K2; k0 += 64) {
#pragma unroll
    for (int i = 0; i < 8; ++i) {
      __builtin_amdgcn_global_load_lds((const __attribute__((address_space(1))) void*)ga[i],
                                       (__attribute__((address_space(3))) void*)la[i], 16, 0, 0);
      ga[i] += 64;
    }
#pragma unroll
    for (int i = 0; i < 4; ++i) {
      __builtin_amdgcn_global_load_lds((const __attribute__((address_space(1))) void*)gb[i],
                                       (__attribute__((address_space(3))) void*)lb[i], 16, 0, 0);
      gb[i] += 64;
    }
    __syncthreads();
#pragma unroll
    for (int kk = 0; kk < 2; ++kk) {
      s16x8 af[4], bf[4];
#pragma unroll
      for (int mt = 0; mt < 4; ++mt)
        af[mt] = *reinterpret_cast<const s16x8*>(
            sAb + (wm * 64 + mt * 16 + l16) * 128 + ((kk * 64 + lk * 16) ^ swa));
#pragma unroll
      for (int nt = 0; nt < 4; ++nt)
        bf[nt] = *reinterpret_cast<const s16x8*>(
            sBb + (nt * 16 + l16) * 128 + ((kk * 64 + lk * 16) ^ swa));
#pragma unroll
      for (int mt = 0; mt < 4; ++mt)
#pragma unroll
        for (int nt = 0; nt < 4; ++nt)
          acc[mt][nt] = __builtin_amdgcn_mfma_f32_16x16x32_bf16(af[mt], bf[nt], acc[mt][nt], 0, 0, 0);
    }
    __syncthreads();
  }

  // ---- merge K-halves through LDS ----
  if (ks == 1) {
    float* mb = reinterpret_cast<float*>(smem) + wm * 4096;
#pragma unroll
    for (int mt = 0; mt < 4; ++mt)
#pragma unroll
      for (int nt = 0; nt < 4; ++nt)
        *reinterpret_cast<f32x4*>(mb + ((mt * 4 + nt) * 64 + lane) * 4) = acc[mt][nt];
  }
  __syncthreads();
  if (ks == 1) return;
  {
    const float* mb = reinterpret_cast<const float*>(smem) + wm * 4096;
#pragma unroll
    for (int mt = 0; mt < 4; ++mt)
#pragma unroll
      for (int nt = 0; nt < 4; ++nt)
        acc[mt][nt] += *reinterpret_cast<const f32x4*>(mb + ((mt * 4 + nt) * 64 + lane) * 4);
  }

#pragma unroll
  for (int mt = 0; mt < 4; ++mt) {
#pragma unroll
    for (int nt = 0; nt < 4; ++nt) {
      const int col = n0 + nt * 16 + l16;
      const int row0 = m0 + wm * 64 + mt * 16 + lk * 4;
      if (OM == 2 && col >= 1024) {
        int b = row0 >> 11, kv = row0 & 2047;
        int h = (col >> 6) & 15, d = col & 63;
        ushort4 o;
        o.x = f2b(acc[mt][nt][0]); o.y = f2b(acc[mt][nt][1]);
        o.z = f2b(acc[mt][nt][2]); o.w = f2b(acc[mt][nt][3]);
        *reinterpret_cast<ushort4*>(VTp + (((size_t)(b * 16 + h) * 64 + d) * 2048 + kv)) = o;
      } else {
#pragma unroll
        for (int j = 0; j < 4; ++j) {
          int row = row0 + j;
          if (OM == 3)      Cb[(size_t)row * N + col] = f2b(acc[mt][nt][j] * QSCALE_);
          else if (OM == 2) Cb[(size_t)row * 1024 + col] = f2b(acc[mt][nt][j]);
          else              Cf[(size_t)row * N + col] = acc[mt][nt][j] + bias[col];
        }
      }
    }
  }
}

// ---------------- flash attention v7b ----------------
// v6 structure; QK row permutation R = r0 + 4*(ct&1) + 32*(ct>>1) (function of
// A-row and ct ONLY -- no lane-lk dependence). Consumer slot map becomes
// kv = lk*8 + j + 4*(ct&1) + 32*(ct>>1), so PV pack is pA=sacc[2f], pB=sacc[2f+1]
// with zero selects. Running stage pointers, per-f V-fragment batch reads.
__global__ __launch_bounds__(512, 4)
void flash_attn(const u16* __restrict__ Kq, const u16* __restrict__ Qb,
                const u16* __restrict__ VT, u16* __restrict__ Rb) {
  __shared__ char smem[65536];
  __shared__ float dmerge[512 * 2];

  const int tid = threadIdx.x;
  const int w = tid >> 6, l = tid & 63;
  const int l16 = l & 15, lk = l >> 4;
  const int half = w >> 2, w4 = w & 3;

  // bijective XCD swizzle: 512 blocks = 8 x 64
  const int bid = blockIdx.x;
  const int wg = ((bid & 7) << 6) | (bid >> 3);
  const int qt = wg & 15, bh = wg >> 4;
  const int b = bh >> 4, h = bh & 15;
  const int qrow0 = qt * 128 + w4 * 32;

  const u16* qp = Qb + ((size_t)(b * LQ_ + qrow0 + l16)) * 1024 + h * 64;
  s16x8 qf[2][2];
#pragma unroll
  for (int g = 0; g < 2; ++g)
#pragma unroll
    for (int ksq = 0; ksq < 2; ++ksq)
      qf[g][ksq] = *reinterpret_cast<const s16x8*>(qp + g * 16 * 1024 + ksq * 32 + lk * 8);

  f32x4 Oacc[2][4], Osum[2];
#pragma unroll
  for (int g = 0; g < 2; ++g) {
    Osum[g] = (f32x4){0.f, 0.f, 0.f, 0.f};
#pragma unroll
    for (int dt = 0; dt < 4; ++dt) Oacc[g][dt] = (f32x4){0.f, 0.f, 0.f, 0.f};
  }

  const u16* Kg = Kq + ((size_t)(b * LKV_ + half * 1024)) * 1024 + h * 64;
  const u16* Vg = VT + ((size_t)bh * 64) * 2048 + half * 1024;
  char* Kl = smem + half * 32768;
  char* Vl = smem + half * 32768 + 16384;

  s16x8 ones;
#pragma unroll
  for (int i = 0; i < 8; ++i) ones[i] = (short)0x3F80;

  // QK A-frag row constant (function of l16 only)
  const int r0 = ((l16 >> 2) << 3) + (l16 & 3);
  const int swv = (l16 & 7) << 4;

  // staging: running pointers (strength-reduced)
  const int srow = (tid & 255) >> 3;
  const int scol = (tid & 7) ^ (srow & 7);
  const u16* kp0 = Kg + (size_t)srow * 1024 + scol * 8;
  const u16* kp1 = kp0 + (size_t)32 * 1024;
  const u16* vp0 = Vg + (size_t)srow * 2048 + scol * 8;
  const u16* vp1 = vp0 + (size_t)32 * 2048;
  char* kd0 = Kl + w4 * 1024;
  char* vd0 = Vl + w4 * 1024;

  auto stage = [&](int bb) {
    __builtin_amdgcn_global_load_lds((const __attribute__((address_space(1))) void*)kp0,
                                     (__attribute__((address_space(3))) void*)(kd0 + bb * 8192), 16, 0, 0);
    __builtin_amdgcn_global_load_lds((const __attribute__((address_space(1))) void*)kp1,
                                     (__attribute__((address_space(3))) void*)(kd0 + bb * 8192 + 4096), 16, 0, 0);
    __builtin_amdgcn_global_load_lds((const __attribute__((address_space(1))) void*)vp0,
                                     (__attribute__((address_space(3))) void*)(vd0 + bb * 8192), 16, 0, 0);
    __builtin_amdgcn_global_load_lds((const __attribute__((address_space(1))) void*)vp1,
                                     (__attribute__((address_space(3))) void*)(vd0 + bb * 8192 + 4096), 16, 0, 0);
  };

  stage(0);
  kp0 += 65536; kp1 += 65536; vp0 += 64; vp1 += 64;
  __syncthreads();

  int cur = 0;
  for (int jt = 0; jt < 16; ++jt) {
    if (jt < 15) {
      stage(cur ^ 1);
      kp0 += 65536; kp1 += 65536; vp0 += 64; vp1 += 64;
    }
    const char* kb = Kl + cur * 8192;
    const char* vb = Vl + cur * 8192;

    // ---- S^T = K_perm . Q^T (exp2 domain, no max) ----
    f32x4 sacc[2][4];
#pragma unroll
    for (int g = 0; g < 2; ++g)
#pragma unroll
      for (int ct = 0; ct < 4; ++ct) sacc[g][ct] = (f32x4){0.f, 0.f, 0.f, 0.f};

    __builtin_amdgcn_s_setprio(1);
#pragma unroll
    for (int ct = 0; ct < 4; ++ct) {
      const int R = r0 + ((ct & 1) << 2) + ((ct >> 1) << 5);
      const char* rp = kb + R * 128;
      const int sw = (R & 7) << 4;
      s16x8 ka0 = *reinterpret_cast<const s16x8*>(rp + ((lk * 16) ^ sw));
      s16x8 ka1 = *reinterpret_cast<const s16x8*>(rp + ((64 + lk * 16) ^ sw));
      sacc[0][ct] = __builtin_amdgcn_mfma_f32_16x16x32_bf16(ka0, qf[0][0], sacc[0][ct], 0, 0, 0);
      sacc[0][ct] = __builtin_amdgcn_mfma_f32_16x16x32_bf16(ka1, qf[0][1], sacc[0][ct], 0, 0, 0);
      sacc[1][ct] = __builtin_amdgcn_mfma_f32_16x16x32_bf16(ka0, qf[1][0], sacc[1][ct], 0, 0, 0);
      sacc[1][ct] = __builtin_amdgcn_mfma_f32_16x16x32_bf16(ka1, qf[1][1], sacc[1][ct], 0, 0, 0);
    }
    __builtin_amdgcn_s_setprio(0);

    // ---- P = exp2(S) in-register ----
#pragma unroll
    for (int g = 0; g < 2; ++g)
#pragma unroll
      for (int ct = 0; ct < 4; ++ct)
#pragma unroll
        for (int j = 0; j < 4; ++j)
          sacc[g][ct][j] = exp2f(sacc[g][ct][j]);

    // ---- O^T += VT . P^T ; denominator += ones . P^T (no selects) ----
#pragma unroll
    for (int f = 0; f < 2; ++f) {
      s16x8 va[4];
#pragma unroll
      for (int dt = 0; dt < 4; ++dt)
        va[dt] = *reinterpret_cast<const s16x8*>(vb + (dt * 16 + l16) * 128 + ((f * 64 + lk * 16) ^ swv));
      s16x8 pf[2];
#pragma unroll
      for (int g = 0; g < 2; ++g) {
        const f32x4 pA = sacc[g][2 * f];
        const f32x4 pB = sacc[g][2 * f + 1];
        union { unsigned u[4]; s16x8 v; } pk;
        pk.u[0] = cvtpk(pA[0], pA[1]);
        pk.u[1] = cvtpk(pA[2], pA[3]);
        pk.u[2] = cvtpk(pB[0], pB[1]);
        pk.u[3] = cvtpk(pB[2], pB[3]);
        pf[g] = pk.v;
      }
      __builtin_amdgcn_s_setprio(1);
#pragma unroll
      for (int dt = 0; dt < 4; ++dt) {
        Oacc[0][dt] = __builtin_amdgcn_mfma_f32_16x16x32_bf16(va[dt], pf[0], Oacc[0][dt], 0, 0, 0);
        Oacc[1][dt] = __builtin_amdgcn_mfma_f32_16x16x32_bf16(va[dt], pf[1], Oacc[1][dt], 0, 0, 0);
      }
      Osum[0] = __builtin_amdgcn_mfma_f32_16x16x32_bf16(ones, pf[0], Osum[0], 0, 0, 0);
      Osum[1] = __builtin_amdgcn_mfma_f32_16x16x32_bf16(ones, pf[1], Osum[1], 0, 0, 0);
      __builtin_amdgcn_s_setprio(0);
    }
    __syncthreads();
    cur ^= 1;
  }

  // ---- merge halves through LDS (half-0 staging region, now dead) ----
  if (w >= 4) {
    char* mb = smem + (((w - 4) * 64 + l) * 128);
#pragma unroll
    for (int g = 0; g < 2; ++g)
#pragma unroll
      for (int dt = 0; dt < 4; ++dt)
        *reinterpret_cast<f32x4*>(mb + (((g * 4 + dt) * 16) ^ ((l & 7) << 4))) = Oacc[g][dt];
    dmerge[((w - 4) * 64 + l) * 2 + 0] = Osum[0][0];
    dmerge[((w - 4) * 64 + l) * 2 + 1] = Osum[1][0];
  }
  __syncthreads();
  if (w < 4) {
    const char* mb = smem + ((w * 64 + l) * 128);
#pragma unroll
    for (int g = 0; g < 2; ++g) {
      float inv = 1.f / (Osum[g][0] + dmerge[(w * 64 + l) * 2 + g]);
      u16* op = Rb + ((size_t)(b * LQ_ + qrow0 + g * 16 + l16)) * 1024 + h * 64 + lk * 4;
#pragma unroll
      for (int dt = 0; dt < 4; ++dt) {
        f32x4 o2 = *reinterpret_cast<const f32x4*>(mb + (((g * 4 + dt) * 16) ^ ((l & 7) << 4)));
        f32x4 s = Oacc[g][dt] + o2;
        ushort4 o;
        o.x = f2b(s[0] * inv); o.y = f2b(s[1] * inv);
        o.z = f2b(s[2] * inv); o.w = f2b(s[3] * inv);
        *reinterpret_cast<ushort4*>(op + dt * 16) = o;
      }
    }
  }
}

// ---------------- launch ----------------
extern "C" void kernel_launch(void* const* d_in, const int* in_sizes, int n_in,
                              void* d_out, int out_size, void* d_ws, size_t ws_size,
                              hipStream_t stream) {
  const float* x   = (const float*)d_in[0];
  const float* y   = (const float*)d_in[1];
  const float* Wq  = (const float*)d_in[2];
  const float* Wkv = (const float*)d_in[3];
  const float* Wp  = (const float*)d_in[4];
  const float* bp  = (const float*)d_in[5];
  float* out = (float*)d_out;

  u16* p = (u16*)d_ws;
  u16* xb   = p; p += (size_t)4096 * 1024;
  u16* yb   = p; p += (size_t)4096 * 768;
  u16* WqT  = p; p += (size_t)1024 * 1024;
  u16* WkvT = p; p += (size_t)2048 * 768;
  u16* WpT  = p; p += (size_t)1024 * 1024;
  u16* Qb   = p; p += (size_t)4096 * 1024;
  u16* Kbf  = p; p += (size_t)4096 * 1024;   // K compact [b*2048+kv][h*64+d]
  u16* VTb  = p; p += (size_t)4096 * 1024;   // [32][64][2048]
  u16* Rb   = p; p += (size_t)4096 * 1024;

  cast2_bf16<<<7168, 256, 0, stream>>>(x, xb, y, yb);
  transpose_cast3<<<896, 256, 0, stream>>>(Wq, WqT, Wkv, WkvT, Wp, WpT);

  // Q = (x @ Wq) * 0.125*log2e : bf16 [4096,1024]
  gemm_bt<3><<<dim3(32, 16), 256, 0, stream>>>(xb, WqT, Qb, nullptr, nullptr, nullptr, 4096, 1024, 1024);
  // KV = y @ Wkv : K -> Kbf, V -> VTb (transposed in epilogue)
  gemm_bt<2><<<dim3(32, 32), 256, 0, stream>>>(yb, WkvT, Kbf, nullptr, nullptr, VTb, 4096, 2048, 768);
  // attention -> Rb [4096,1024] (halves merged in-block)
  flash_attn<<<512, 512, 0, stream>>>(Kbf, Qb, VTb, Rb);
  // out = Rb @ Wproj + bias : fp32 [4096,1024]
  gemm_bt<1><<<dim3(32, 16), 256, 0, stream>>>(Rb, WpT, nullptr, out, bp, nullptr, 4096, 1024, 1024);
}

// Round 9
// 121.008 us; speedup vs baseline: 2.1351x; 1.0348x over previous
//
#include <hip/hip_runtime.h>
#include <hip/hip_bf16.h>
#include <cstdint>

typedef unsigned short u16;
typedef __attribute__((ext_vector_type(4))) float f32x4;
typedef __attribute__((ext_vector_type(8))) short s16x8;
typedef __attribute__((ext_vector_type(4))) unsigned int u32x4;

#define B_    2
#define LQ_   2048
#define LKV_  2048
#define H_    16
// softmax scale folded into Q at GEMM epilogue: 0.125 * log2(e)
#define QSCALE_ 0.18033688011112042f

__device__ __forceinline__ u16 f2b(float f) {
  union { float f; unsigned int u; } v; v.f = f;
  unsigned int r = v.u + 0x7fffu + ((v.u >> 16) & 1u);
  return (u16)(r >> 16);
}

__device__ __forceinline__ unsigned cvtpk(float lo, float hi) {
  unsigned r;
  asm("v_cvt_pk_bf16_f32 %0, %1, %2" : "=v"(r) : "v"(lo), "v"(hi));
  return r;
}

#if __has_builtin(__builtin_amdgcn_exp2f)
__device__ __forceinline__ float fexp2(float x) { return __builtin_amdgcn_exp2f(x); }
#else
__device__ __forceinline__ float fexp2(float x) {
  float r; asm volatile("v_exp_f32 %0, %1" : "=v"(r) : "v"(x)); return r;
}
#endif

#define GLOAD(g, l) __builtin_amdgcn_global_load_lds( \
    (const __attribute__((address_space(1))) void*)(g), \
    (__attribute__((address_space(3))) void*)(l), 16, 0, 0)

// ---------------- prep: fused input casts + weight transposes ----------------
__global__ void prep(const float* __restrict__ x, u16* __restrict__ xb,
                     const float* __restrict__ y, u16* __restrict__ yb,
                     const float* __restrict__ Wq, u16* __restrict__ WqT,
                     const float* __restrict__ Wkv, u16* __restrict__ WkvT,
                     const float* __restrict__ Wp, u16* __restrict__ WpT) {
  __shared__ u16 tile[64][65];
  const int bid = blockIdx.x;
  const int t = threadIdx.x;
  if (bid < 7168) {
    const float* in; u16* out; int i;
    if (bid < 4096) { in = x; out = xb; i = (bid * 256 + t) * 4; }
    else            { in = y; out = yb; i = ((bid - 4096) * 256 + t) * 4; }
    float4 v = *reinterpret_cast<const float4*>(in + i);
    ushort4 r;
    r.x = f2b(v.x); r.y = f2b(v.y); r.z = f2b(v.z); r.w = f2b(v.w);
    *reinterpret_cast<ushort4*>(out + i) = r;
    return;
  }
  const int tb = bid - 7168;
  const float* W; u16* WT; int K, N, bx, by;
  if (tb < 256)      { W = Wq;  WT = WqT;  K = 1024; N = 1024; bx = tb & 15;         by = tb >> 4; }
  else if (tb < 640) { W = Wkv; WT = WkvT; K = 768;  N = 2048; bx = (tb - 256) & 31; by = (tb - 256) >> 5; }
  else               { W = Wp;  WT = WpT;  K = 1024; N = 1024; bx = (tb - 640) & 15; by = (tb - 640) >> 4; }
  const int n0 = bx * 64, k0 = by * 64;
#pragma unroll
  for (int p = 0; p < 4; ++p) {
    int r = (t >> 4) + p * 16;
    int c = (t & 15) * 4;
    float4 v = *reinterpret_cast<const float4*>(W + (size_t)(k0 + r) * N + n0 + c);
    tile[r][c + 0] = f2b(v.x);
    tile[r][c + 1] = f2b(v.y);
    tile[r][c + 2] = f2b(v.z);
    tile[r][c + 3] = f2b(v.w);
  }
  __syncthreads();
#pragma unroll
  for (int p = 0; p < 4; ++p) {
    int nr = (t >> 4) + p * 16;
    int kc = (t & 15) * 4;
    ushort4 o;
    o.x = tile[kc + 0][nr];
    o.y = tile[kc + 1][nr];
    o.z = tile[kc + 2][nr];
    o.w = tile[kc + 3][nr];
    *reinterpret_cast<ushort4*>(WT + (size_t)(n0 + nr) * K + k0 + kc) = o;
  }
}

// ---------------- GEMM v3: split-K x2, BK=32, double-buffered ----------------
// tile 128x64, 4 waves = 2(wm) x 2(ks); wave-tile 64x64 over K/2.
// LDS rows 64B (4 chunks); chunk-swizzle s(row)=(row>>1)&3 (2-way free reads).
// Stage next buf before compute (flash-style, 1 barrier/step).
// K-halves merged through LDS (f32), ks==0 waves write C.
// OM==1: fp32 out + bias; OM==2: KV split; OM==3: bf16 * QSCALE_.
template <int OM>
__global__ __launch_bounds__(256, 3)
void gemm_bt(const u16* __restrict__ A, const u16* __restrict__ BT,
             u16* __restrict__ Cb, float* __restrict__ Cf,
             const float* __restrict__ bias, u16* __restrict__ VTp,
             int M, int N, int K) {
  // A: [hh][buf][128 rows][64B] = 32KB; B @32768: [hh][buf][64 rows][64B] = 16KB
  __shared__ __attribute__((aligned(16))) char smem[49152];
  const int tid = threadIdx.x;
  const int w = tid >> 6, lane = tid & 63;
  const int l16 = lane & 15, lk = lane >> 4;
  const int m0 = blockIdx.x * 128, n0 = blockIdx.y * 64;
  const int wm = w >> 1, ks = w & 1;
  const int K2 = K >> 1;
  const int NS = K2 >> 5;

  f32x4 acc[4][4];
#pragma unroll
  for (int i = 0; i < 4; ++i)
#pragma unroll
    for (int j = 0; j < 4; ++j)
      acc[i][j] = (f32x4){0.f, 0.f, 0.f, 0.f};

  // staging constants: thread -> row tid>>2, pos tid&3; source chunk pre-XOR s(row)=(tid>>3)&3
  const int srow = tid >> 2;
  const int sc = ((tid & 3) ^ ((tid >> 3) & 3)) * 8;
  const u16* gA0 = A + (size_t)(m0 + srow) * K + sc;          // half 0
  const u16* gA1 = gA0 + K2;                                  // half 1
  const u16* gB0 = BT + (size_t)(n0 + srow) * K + sc;
  const u16* gB1 = gB0 + K2;
  const size_t rstep = (size_t)64 * K;                        // A round-1 row offset
  char* ldsA = smem;                                          // + hh*16384 + bb*8192 + i*4096 + w*1024
  char* ldsB = smem + 32768;                                  // + hh*8192 + bb*4096 + w*1024

  auto stage = [&](int k0, int bb) {
    GLOAD(gA0 + k0,         ldsA + bb * 8192 + w * 1024);
    GLOAD(gA0 + k0 + rstep, ldsA + bb * 8192 + 4096 + w * 1024);
    GLOAD(gA1 + k0,         ldsA + 16384 + bb * 8192 + w * 1024);
    GLOAD(gA1 + k0 + rstep, ldsA + 16384 + bb * 8192 + 4096 + w * 1024);
    GLOAD(gB0 + k0,         ldsB + bb * 4096 + w * 1024);
    GLOAD(gB1 + k0,         ldsB + 8192 + bb * 4096 + w * 1024);
  };

  const char* sAb = smem + ks * 16384;
  const char* sBb = smem + 32768 + ks * 8192;
  const int swl = ((l16 >> 1) & 3) << 4;

  stage(0, 0);
  __syncthreads();
  int cur = 0;
  for (int s = 0; s < NS; ++s) {
    if (s + 1 < NS) stage((s + 1) * 32, cur ^ 1);
    s16x8 af[4], bf[4];
#pragma unroll
    for (int mt = 0; mt < 4; ++mt)
      af[mt] = *reinterpret_cast<const s16x8*>(
          sAb + cur * 8192 + (wm * 64 + mt * 16 + l16) * 64 + ((lk * 16) ^ swl));
#pragma unroll
    for (int nt = 0; nt < 4; ++nt)
      bf[nt] = *reinterpret_cast<const s16x8*>(
          sBb + cur * 4096 + (nt * 16 + l16) * 64 + ((lk * 16) ^ swl));
    __builtin_amdgcn_s_setprio(1);
#pragma unroll
    for (int mt = 0; mt < 4; ++mt)
#pragma unroll
      for (int nt = 0; nt < 4; ++nt)
        acc[mt][nt] = __builtin_amdgcn_mfma_f32_16x16x32_bf16(af[mt], bf[nt], acc[mt][nt], 0, 0, 0);
    __builtin_amdgcn_s_setprio(0);
    __syncthreads();
    cur ^= 1;
  }

  // ---- merge K-halves through LDS ----
  if (ks == 1) {
    float* mb = reinterpret_cast<float*>(smem) + wm * 4096;
#pragma unroll
    for (int mt = 0; mt < 4; ++mt)
#pragma unroll
      for (int nt = 0; nt < 4; ++nt)
        *reinterpret_cast<f32x4*>(mb + ((mt * 4 + nt) * 64 + lane) * 4) = acc[mt][nt];
  }
  __syncthreads();
  if (ks == 1) return;
  {
    const float* mb = reinterpret_cast<const float*>(smem) + wm * 4096;
#pragma unroll
    for (int mt = 0; mt < 4; ++mt)
#pragma unroll
      for (int nt = 0; nt < 4; ++nt)
        acc[mt][nt] += *reinterpret_cast<const f32x4*>(mb + ((mt * 4 + nt) * 64 + lane) * 4);
  }

#pragma unroll
  for (int mt = 0; mt < 4; ++mt) {
#pragma unroll
    for (int nt = 0; nt < 4; ++nt) {
      const int col = n0 + nt * 16 + l16;
      const int row0 = m0 + wm * 64 + mt * 16 + lk * 4;
      if (OM == 2 && col >= 1024) {
        int b = row0 >> 11, kv = row0 & 2047;
        int h = (col >> 6) & 15, d = col & 63;
        ushort4 o;
        o.x = f2b(acc[mt][nt][0]); o.y = f2b(acc[mt][nt][1]);
        o.z = f2b(acc[mt][nt][2]); o.w = f2b(acc[mt][nt][3]);
        *reinterpret_cast<ushort4*>(VTp + (((size_t)(b * 16 + h) * 64 + d) * 2048 + kv)) = o;
      } else {
#pragma unroll
        for (int j = 0; j < 4; ++j) {
          int row = row0 + j;
          if (OM == 3)      Cb[(size_t)row * N + col] = f2b(acc[mt][nt][j] * QSCALE_);
          else if (OM == 2) Cb[(size_t)row * 1024 + col] = f2b(acc[mt][nt][j]);
          else              Cf[(size_t)row * N + col] = acc[mt][nt][j] + bias[col];
        }
      }
    }
  }
}

// ---------------- flash attention v8 ----------------
// v7b structure; K-swizzle fn changed to s(row) = (row&3)|(bit3(row)<<2) so a
// read phase's 16 lanes spread over all 8 chunk positions (2-way, free).
// s(R) is lane-constant (R bits: 0-1 = l16&3, bit3 = l16>>2 bit0).
// exp2 via raw v_exp_f32.
__global__ __launch_bounds__(512, 4)
void flash_attn(const u16* __restrict__ Kq, const u16* __restrict__ Qb,
                const u16* __restrict__ VT, u16* __restrict__ Rb) {
  __shared__ __attribute__((aligned(16))) char smem[65536];
  __shared__ float dmerge[512 * 2];

  const int tid = threadIdx.x;
  const int w = tid >> 6, l = tid & 63;
  const int l16 = l & 15, lk = l >> 4;
  const int half = w >> 2, w4 = w & 3;

  // bijective XCD swizzle: 512 blocks = 8 x 64
  const int bid = blockIdx.x;
  const int wg = ((bid & 7) << 6) | (bid >> 3);
  const int qt = wg & 15, bh = wg >> 4;
  const int b = bh >> 4, h = bh & 15;
  const int qrow0 = qt * 128 + w4 * 32;

  const u16* qp = Qb + ((size_t)(b * LQ_ + qrow0 + l16)) * 1024 + h * 64;
  s16x8 qf[2][2];
#pragma unroll
  for (int g = 0; g < 2; ++g)
#pragma unroll
    for (int ksq = 0; ksq < 2; ++ksq)
      qf[g][ksq] = *reinterpret_cast<const s16x8*>(qp + g * 16 * 1024 + ksq * 32 + lk * 8);

  f32x4 Oacc[2][4], Osum[2];
#pragma unroll
  for (int g = 0; g < 2; ++g) {
    Osum[g] = (f32x4){0.f, 0.f, 0.f, 0.f};
#pragma unroll
    for (int dt = 0; dt < 4; ++dt) Oacc[g][dt] = (f32x4){0.f, 0.f, 0.f, 0.f};
  }

  const u16* Kg = Kq + ((size_t)(b * LKV_ + half * 1024)) * 1024 + h * 64;
  const u16* Vg = VT + ((size_t)bh * 64) * 2048 + half * 1024;
  char* Kl = smem + half * 32768;
  char* Vl = smem + half * 32768 + 16384;

  s16x8 ones;
#pragma unroll
  for (int i = 0; i < 8; ++i) ones[i] = (short)0x3F80;

  // QK A-frag row constant and lane-constant K swizzle
  const int r0 = ((l16 >> 2) << 3) + (l16 & 3);
  const int swk = ((l16 & 3) | (((l16 >> 2) & 1) << 2)) << 4;
  const int swv = (l16 & 7) << 4;

  // staging: running pointers; K source pre-XOR with s(row), V with row&7
  const int srow = (tid & 255) >> 3;
  const int sck = (tid & 7) ^ ((srow & 3) | (((srow >> 3) & 1) << 2));
  const int scv = (tid & 7) ^ (srow & 7);
  const u16* kp0 = Kg + (size_t)srow * 1024 + sck * 8;
  const u16* kp1 = kp0 + (size_t)32 * 1024;
  const u16* vp0 = Vg + (size_t)srow * 2048 + scv * 8;
  const u16* vp1 = vp0 + (size_t)32 * 2048;
  char* kd0 = Kl + w4 * 1024;
  char* vd0 = Vl + w4 * 1024;

  auto stage = [&](int bb) {
    GLOAD(kp0, kd0 + bb * 8192);
    GLOAD(kp1, kd0 + bb * 8192 + 4096);
    GLOAD(vp0, vd0 + bb * 8192);
    GLOAD(vp1, vd0 + bb * 8192 + 4096);
  };

  stage(0);
  kp0 += 65536; kp1 += 65536; vp0 += 64; vp1 += 64;
  __syncthreads();

  int cur = 0;
  for (int jt = 0; jt < 16; ++jt) {
    if (jt < 15) {
      stage(cur ^ 1);
      kp0 += 65536; kp1 += 65536; vp0 += 64; vp1 += 64;
    }
    const char* kb = Kl + cur * 8192;
    const char* vb = Vl + cur * 8192;

    // ---- S^T = K_perm . Q^T (exp2 domain, no max) ----
    f32x4 sacc[2][4];
#pragma unroll
    for (int g = 0; g < 2; ++g)
#pragma unroll
      for (int ct = 0; ct < 4; ++ct) sacc[g][ct] = (f32x4){0.f, 0.f, 0.f, 0.f};

    __builtin_amdgcn_s_setprio(1);
#pragma unroll
    for (int ct = 0; ct < 4; ++ct) {
      const int R = r0 + ((ct & 1) << 2) + ((ct >> 1) << 5);
      const char* rp = kb + R * 128;
      s16x8 ka0 = *reinterpret_cast<const s16x8*>(rp + ((lk * 16) ^ swk));
      s16x8 ka1 = *reinterpret_cast<const s16x8*>(rp + ((64 + lk * 16) ^ swk));
      sacc[0][ct] = __builtin_amdgcn_mfma_f32_16x16x32_bf16(ka0, qf[0][0], sacc[0][ct], 0, 0, 0);
      sacc[0][ct] = __builtin_amdgcn_mfma_f32_16x16x32_bf16(ka1, qf[0][1], sacc[0][ct], 0, 0, 0);
      sacc[1][ct] = __builtin_amdgcn_mfma_f32_16x16x32_bf16(ka0, qf[1][0], sacc[1][ct], 0, 0, 0);
      sacc[1][ct] = __builtin_amdgcn_mfma_f32_16x16x32_bf16(ka1, qf[1][1], sacc[1][ct], 0, 0, 0);
    }
    __builtin_amdgcn_s_setprio(0);

    // ---- P = exp2(S) in-register (raw v_exp_f32) ----
#pragma unroll
    for (int g = 0; g < 2; ++g)
#pragma unroll
      for (int ct = 0; ct < 4; ++ct)
#pragma unroll
        for (int j = 0; j < 4; ++j)
          sacc[g][ct][j] = fexp2(sacc[g][ct][j]);

    // ---- O^T += VT . P^T ; denominator += ones . P^T (no selects) ----
#pragma unroll
    for (int f = 0; f < 2; ++f) {
      s16x8 va[4];
#pragma unroll
      for (int dt = 0; dt < 4; ++dt)
        va[dt] = *reinterpret_cast<const s16x8*>(vb + (dt * 16 + l16) * 128 + ((f * 64 + lk * 16) ^ swv));
      s16x8 pf[2];
#pragma unroll
      for (int g = 0; g < 2; ++g) {
        const f32x4 pA = sacc[g][2 * f];
        const f32x4 pB = sacc[g][2 * f + 1];
        union { unsigned u[4]; s16x8 v; } pk;
        pk.u[0] = cvtpk(pA[0], pA[1]);
        pk.u[1] = cvtpk(pA[2], pA[3]);
        pk.u[2] = cvtpk(pB[0], pB[1]);
        pk.u[3] = cvtpk(pB[2], pB[3]);
        pf[g] = pk.v;
      }
      __builtin_amdgcn_s_setprio(1);
#pragma unroll
      for (int dt = 0; dt < 4; ++dt) {
        Oacc[0][dt] = __builtin_amdgcn_mfma_f32_16x16x32_bf16(va[dt], pf[0], Oacc[0][dt], 0, 0, 0);
        Oacc[1][dt] = __builtin_amdgcn_mfma_f32_16x16x32_bf16(va[dt], pf[1], Oacc[1][dt], 0, 0, 0);
      }
      Osum[0] = __builtin_amdgcn_mfma_f32_16x16x32_bf16(ones, pf[0], Osum[0], 0, 0, 0);
      Osum[1] = __builtin_amdgcn_mfma_f32_16x16x32_bf16(ones, pf[1], Osum[1], 0, 0, 0);
      __builtin_amdgcn_s_setprio(0);
    }
    __syncthreads();
    cur ^= 1;
  }

  // ---- merge halves through LDS (half-0 staging region, now dead) ----
  if (w >= 4) {
    char* mb = smem + (((w - 4) * 64 + l) * 128);
#pragma unroll
    for (int g = 0; g < 2; ++g)
#pragma unroll
      for (int dt = 0; dt < 4; ++dt)
        *reinterpret_cast<f32x4*>(mb + (((g * 4 + dt) * 16) ^ ((l & 7) << 4))) = Oacc[g][dt];
    dmerge[((w - 4) * 64 + l) * 2 + 0] = Osum[0][0];
    dmerge[((w - 4) * 64 + l) * 2 + 1] = Osum[1][0];
  }
  __syncthreads();
  if (w < 4) {
    const char* mb = smem + ((w * 64 + l) * 128);
#pragma unroll
    for (int g = 0; g < 2; ++g) {
      float inv = 1.f / (Osum[g][0] + dmerge[(w * 64 + l) * 2 + g]);
      u16* op = Rb + ((size_t)(b * LQ_ + qrow0 + g * 16 + l16)) * 1024 + h * 64 + lk * 4;
#pragma unroll
      for (int dt = 0; dt < 4; ++dt) {
        f32x4 o2 = *reinterpret_cast<const f32x4*>(mb + (((g * 4 + dt) * 16) ^ ((l & 7) << 4)));
        f32x4 s = Oacc[g][dt] + o2;
        ushort4 o;
        o.x = f2b(s[0] * inv); o.y = f2b(s[1] * inv);
        o.z = f2b(s[2] * inv); o.w = f2b(s[3] * inv);
        *reinterpret_cast<ushort4*>(op + dt * 16) = o;
      }
    }
  }
}

// ---------------- launch ----------------
extern "C" void kernel_launch(void* const* d_in, const int* in_sizes, int n_in,
                              void* d_out, int out_size, void* d_ws, size_t ws_size,
                              hipStream_t stream) {
  const float* x   = (const float*)d_in[0];
  const float* y   = (const float*)d_in[1];
  const float* Wq  = (const float*)d_in[2];
  const float* Wkv = (const float*)d_in[3];
  const float* Wp  = (const float*)d_in[4];
  const float* bp  = (const float*)d_in[5];
  float* out = (float*)d_out;

  u16* p = (u16*)d_ws;
  u16* xb   = p; p += (size_t)4096 * 1024;
  u16* yb   = p; p += (size_t)4096 * 768;
  u16* WqT  = p; p += (size_t)1024 * 1024;
  u16* WkvT = p; p += (size_t)2048 * 768;
  u16* WpT  = p; p += (size_t)1024 * 1024;
  u16* Qb   = p; p += (size_t)4096 * 1024;
  u16* Kbf  = p; p += (size_t)4096 * 1024;   // K compact [b*2048+kv][h*64+d]
  u16* VTb  = p; p += (size_t)4096 * 1024;   // [32][64][2048]
  u16* Rb   = p; p += (size_t)4096 * 1024;

  prep<<<8064, 256, 0, stream>>>(x, xb, y, yb, Wq, WqT, Wkv, WkvT, Wp, WpT);

  // Q = (x @ Wq) * 0.125*log2e : bf16 [4096,1024]
  gemm_bt<3><<<dim3(32, 16), 256, 0, stream>>>(xb, WqT, Qb, nullptr, nullptr, nullptr, 4096, 1024, 1024);
  // KV = y @ Wkv : K -> Kbf, V -> VTb (transposed in epilogue)
  gemm_bt<2><<<dim3(32, 32), 256, 0, stream>>>(yb, WkvT, Kbf, nullptr, nullptr, VTb, 4096, 2048, 768);
  // attention -> Rb [4096,1024] (halves merged in-block)
  flash_attn<<<512, 512, 0, stream>>>(Kbf, Qb, VTb, Rb);
  // out = Rb @ Wproj + bias : fp32 [4096,1024]
  gemm_bt<1><<<dim3(32, 16), 256, 0, stream>>>(Rb, WpT, nullptr, out, bp, nullptr, 4096, 1024, 1024);
}

// Round 10
// 99.619 us; speedup vs baseline: 2.5936x; 1.2147x over previous
//
#include <hip/hip_runtime.h>
#include <hip/hip_bf16.h>
#include <cstdint>

typedef unsigned short u16;
typedef __attribute__((ext_vector_type(4))) float f32x4;
typedef __attribute__((ext_vector_type(8))) short s16x8;
typedef __attribute__((ext_vector_type(4))) unsigned int u32x4;

#define B_    2
#define LQ_   2048
#define LKV_  2048
#define H_    16
// softmax scale folded into Q at GEMM epilogue: 0.125 * log2(e)
#define QSCALE_ 0.18033688011112042f

__device__ __forceinline__ u16 f2b(float f) {
  union { float f; unsigned int u; } v; v.f = f;
  unsigned int r = v.u + 0x7fffu + ((v.u >> 16) & 1u);
  return (u16)(r >> 16);
}

__device__ __forceinline__ unsigned cvtpk(float lo, float hi) {
  unsigned r;
  asm("v_cvt_pk_bf16_f32 %0, %1, %2" : "=v"(r) : "v"(lo), "v"(hi));
  return r;
}

#if __has_builtin(__builtin_amdgcn_exp2f)
__device__ __forceinline__ float fexp2(float x) { return __builtin_amdgcn_exp2f(x); }
#else
__device__ __forceinline__ float fexp2(float x) {
  float r; asm volatile("v_exp_f32 %0, %1" : "=v"(r) : "v"(x)); return r;
}
#endif

#define GLOAD(g, l) __builtin_amdgcn_global_load_lds( \
    (const __attribute__((address_space(1))) void*)(g), \
    (__attribute__((address_space(3))) void*)(l), 16, 0, 0)

// ---------------- prep: fused input casts + weight transposes ----------------
__global__ void prep(const float* __restrict__ x, u16* __restrict__ xb,
                     const float* __restrict__ y, u16* __restrict__ yb,
                     const float* __restrict__ Wq, u16* __restrict__ WqT,
                     const float* __restrict__ Wkv, u16* __restrict__ WkvT,
                     const float* __restrict__ Wp, u16* __restrict__ WpT) {
  __shared__ u16 tile[64][65];
  const int bid = blockIdx.x;
  const int t = threadIdx.x;
  if (bid < 7168) {
    const float* in; u16* out; int i;
    if (bid < 4096) { in = x; out = xb; i = (bid * 256 + t) * 4; }
    else            { in = y; out = yb; i = ((bid - 4096) * 256 + t) * 4; }
    float4 v = *reinterpret_cast<const float4*>(in + i);
    ushort4 r;
    r.x = f2b(v.x); r.y = f2b(v.y); r.z = f2b(v.z); r.w = f2b(v.w);
    *reinterpret_cast<ushort4*>(out + i) = r;
    return;
  }
  const int tb = bid - 7168;
  const float* W; u16* WT; int K, N, bx, by;
  if (tb < 256)      { W = Wq;  WT = WqT;  K = 1024; N = 1024; bx = tb & 15;         by = tb >> 4; }
  else if (tb < 640) { W = Wkv; WT = WkvT; K = 768;  N = 2048; bx = (tb - 256) & 31; by = (tb - 256) >> 5; }
  else               { W = Wp;  WT = WpT;  K = 1024; N = 1024; bx = (tb - 640) & 15; by = (tb - 640) >> 4; }
  const int n0 = bx * 64, k0 = by * 64;
#pragma unroll
  for (int p = 0; p < 4; ++p) {
    int r = (t >> 4) + p * 16;
    int c = (t & 15) * 4;
    float4 v = *reinterpret_cast<const float4*>(W + (size_t)(k0 + r) * N + n0 + c);
    tile[r][c + 0] = f2b(v.x);
    tile[r][c + 1] = f2b(v.y);
    tile[r][c + 2] = f2b(v.z);
    tile[r][c + 3] = f2b(v.w);
  }
  __syncthreads();
#pragma unroll
  for (int p = 0; p < 4; ++p) {
    int nr = (t >> 4) + p * 16;
    int kc = (t & 15) * 4;
    ushort4 o;
    o.x = tile[kc + 0][nr];
    o.y = tile[kc + 1][nr];
    o.z = tile[kc + 2][nr];
    o.w = tile[kc + 3][nr];
    *reinterpret_cast<ushort4*>(WT + (size_t)(n0 + nr) * K + k0 + kc) = o;
  }
}

// ---------------- GEMM v4 core: 128x64 tile, BK=64, dbuf, 1 barrier/step ----------------
// 4 waves = 2(wm) x 2(wn); wave-tile 64x32; no split-K.
// LDS rows 128B, chunk swizzle (row&7) (8 distinct chunks per 8-lane phase: free).
// Stage targets the other buffer -> single __syncthreads per step.
// OM==1: fp32 out + bias; OM==2: KV split (K compact / V transposed); OM==3: bf16 * QSCALE_.
__device__ __forceinline__ void gemm_core(
    int OM, const u16* __restrict__ A, const u16* __restrict__ BT,
    u16* __restrict__ Cb, float* __restrict__ Cf,
    const float* __restrict__ bias, u16* __restrict__ VTp,
    int N, int K, int m0, int n0, char* smem) {
  const int tid = threadIdx.x;
  const int w = tid >> 6, lane = tid & 63;
  const int l16 = lane & 15, lk = lane >> 4;
  const int wm = w >> 1, wn = w & 1;
  const int NS = K >> 6;

  f32x4 acc[4][2];
#pragma unroll
  for (int i = 0; i < 4; ++i)
#pragma unroll
    for (int j = 0; j < 2; ++j)
      acc[i][j] = (f32x4){0.f, 0.f, 0.f, 0.f};

  // staging: row = tid>>3 (0..31) per round, chunk pre-XOR (row&7)
  const int srow = tid >> 3;
  const int sck = (tid & 7) ^ (srow & 7);
  const u16* gA = A + (size_t)(m0 + srow) * K + sck * 8;
  const u16* gB = BT + (size_t)(n0 + srow) * K + sck * 8;
  char* dA = smem + w * 1024;            // + bb*16384 + i*4096
  char* dB = smem + 32768 + w * 1024;    // + bb*8192 + i*4096

  auto stage = [&](int k0, int bb) {
#pragma unroll
    for (int i = 0; i < 4; ++i)
      GLOAD(gA + (size_t)i * 32 * K + k0, dA + bb * 16384 + i * 4096);
#pragma unroll
    for (int i = 0; i < 2; ++i)
      GLOAD(gB + (size_t)i * 32 * K + k0, dB + bb * 8192 + i * 4096);
  };

  const int swa = (l16 & 7) << 4;

  stage(0, 0);
  __syncthreads();
  int cur = 0;
  for (int s = 0; s < NS; ++s) {
    if (s + 1 < NS) stage((s + 1) * 64, cur ^ 1);
    const char* sAb = smem + cur * 16384;
    const char* sBb = smem + 32768 + cur * 8192;
#pragma unroll
    for (int kk = 0; kk < 2; ++kk) {
      s16x8 af[4], bf[2];
#pragma unroll
      for (int mt = 0; mt < 4; ++mt)
        af[mt] = *reinterpret_cast<const s16x8*>(
            sAb + (wm * 64 + mt * 16 + l16) * 128 + ((kk * 64 + lk * 16) ^ swa));
#pragma unroll
      for (int nt = 0; nt < 2; ++nt)
        bf[nt] = *reinterpret_cast<const s16x8*>(
            sBb + (wn * 32 + nt * 16 + l16) * 128 + ((kk * 64 + lk * 16) ^ swa));
      __builtin_amdgcn_s_setprio(1);
#pragma unroll
      for (int mt = 0; mt < 4; ++mt)
#pragma unroll
        for (int nt = 0; nt < 2; ++nt)
          acc[mt][nt] = __builtin_amdgcn_mfma_f32_16x16x32_bf16(af[mt], bf[nt], acc[mt][nt], 0, 0, 0);
      __builtin_amdgcn_s_setprio(0);
    }
    __syncthreads();
    cur ^= 1;
  }

#pragma unroll
  for (int mt = 0; mt < 4; ++mt) {
#pragma unroll
    for (int nt = 0; nt < 2; ++nt) {
      const int col = n0 + wn * 32 + nt * 16 + l16;
      const int row0 = m0 + wm * 64 + mt * 16 + lk * 4;
      if (OM == 2 && col >= 1024) {
        int b = row0 >> 11, kv = row0 & 2047;
        int h = (col >> 6) & 15, d = col & 63;
        ushort4 o;
        o.x = f2b(acc[mt][nt][0]); o.y = f2b(acc[mt][nt][1]);
        o.z = f2b(acc[mt][nt][2]); o.w = f2b(acc[mt][nt][3]);
        *reinterpret_cast<ushort4*>(VTp + (((size_t)(b * 16 + h) * 64 + d) * 2048 + kv)) = o;
      } else {
#pragma unroll
        for (int j = 0; j < 4; ++j) {
          int row = row0 + j;
          if (OM == 3)      Cb[(size_t)row * N + col] = f2b(acc[mt][nt][j] * QSCALE_);
          else if (OM == 2) Cb[(size_t)row * 1024 + col] = f2b(acc[mt][nt][j]);
          else              Cf[(size_t)row * N + col] = acc[mt][nt][j] + bias[col];
        }
      }
    }
  }
}

// Q-GEMM (blocks 0..511) + KV-GEMM (blocks 512..1535) in one launch
__global__ __launch_bounds__(256, 3)
void gemm_qkv(const u16* __restrict__ xb, const u16* __restrict__ WqT,
              const u16* __restrict__ yb, const u16* __restrict__ WkvT,
              u16* __restrict__ Qb, u16* __restrict__ Kbf, u16* __restrict__ VTb) {
  __shared__ __attribute__((aligned(16))) char smem[49152];
  const int bid = blockIdx.x;
  if (bid < 512) {
    gemm_core(3, xb, WqT, Qb, nullptr, nullptr, nullptr,
              1024, 1024, (bid & 31) * 128, (bid >> 5) * 64, smem);
  } else {
    const int t = bid - 512;
    gemm_core(2, yb, WkvT, Kbf, nullptr, nullptr, VTb,
              2048, 768, (t & 31) * 128, (t >> 5) * 64, smem);
  }
}

__global__ __launch_bounds__(256, 3)
void gemm_proj(const u16* __restrict__ Rb, const u16* __restrict__ WpT,
               float* __restrict__ out, const float* __restrict__ bias) {
  __shared__ __attribute__((aligned(16))) char smem[49152];
  const int bid = blockIdx.x;
  gemm_core(1, Rb, WpT, nullptr, out, bias, nullptr,
            1024, 1024, (bid & 31) * 128, (bid >> 5) * 64, smem);
}

// ---------------- flash attention v8 (unchanged from r9 -- measured good) ----------------
__global__ __launch_bounds__(512, 4)
void flash_attn(const u16* __restrict__ Kq, const u16* __restrict__ Qb,
                const u16* __restrict__ VT, u16* __restrict__ Rb) {
  __shared__ __attribute__((aligned(16))) char smem[65536];
  __shared__ float dmerge[512 * 2];

  const int tid = threadIdx.x;
  const int w = tid >> 6, l = tid & 63;
  const int l16 = l & 15, lk = l >> 4;
  const int half = w >> 2, w4 = w & 3;

  // bijective XCD swizzle: 512 blocks = 8 x 64
  const int bid = blockIdx.x;
  const int wg = ((bid & 7) << 6) | (bid >> 3);
  const int qt = wg & 15, bh = wg >> 4;
  const int b = bh >> 4, h = bh & 15;
  const int qrow0 = qt * 128 + w4 * 32;

  const u16* qp = Qb + ((size_t)(b * LQ_ + qrow0 + l16)) * 1024 + h * 64;
  s16x8 qf[2][2];
#pragma unroll
  for (int g = 0; g < 2; ++g)
#pragma unroll
    for (int ksq = 0; ksq < 2; ++ksq)
      qf[g][ksq] = *reinterpret_cast<const s16x8*>(qp + g * 16 * 1024 + ksq * 32 + lk * 8);

  f32x4 Oacc[2][4], Osum[2];
#pragma unroll
  for (int g = 0; g < 2; ++g) {
    Osum[g] = (f32x4){0.f, 0.f, 0.f, 0.f};
#pragma unroll
    for (int dt = 0; dt < 4; ++dt) Oacc[g][dt] = (f32x4){0.f, 0.f, 0.f, 0.f};
  }

  const u16* Kg = Kq + ((size_t)(b * LKV_ + half * 1024)) * 1024 + h * 64;
  const u16* Vg = VT + ((size_t)bh * 64) * 2048 + half * 1024;
  char* Kl = smem + half * 32768;
  char* Vl = smem + half * 32768 + 16384;

  s16x8 ones;
#pragma unroll
  for (int i = 0; i < 8; ++i) ones[i] = (short)0x3F80;

  const int r0 = ((l16 >> 2) << 3) + (l16 & 3);
  const int swk = ((l16 & 3) | (((l16 >> 2) & 1) << 2)) << 4;
  const int swv = (l16 & 7) << 4;

  const int srow = (tid & 255) >> 3;
  const int sck = (tid & 7) ^ ((srow & 3) | (((srow >> 3) & 1) << 2));
  const int scv = (tid & 7) ^ (srow & 7);
  const u16* kp0 = Kg + (size_t)srow * 1024 + sck * 8;
  const u16* kp1 = kp0 + (size_t)32 * 1024;
  const u16* vp0 = Vg + (size_t)srow * 2048 + scv * 8;
  const u16* vp1 = vp0 + (size_t)32 * 2048;
  char* kd0 = Kl + w4 * 1024;
  char* vd0 = Vl + w4 * 1024;

  auto stage = [&](int bb) {
    GLOAD(kp0, kd0 + bb * 8192);
    GLOAD(kp1, kd0 + bb * 8192 + 4096);
    GLOAD(vp0, vd0 + bb * 8192);
    GLOAD(vp1, vd0 + bb * 8192 + 4096);
  };

  stage(0);
  kp0 += 65536; kp1 += 65536; vp0 += 64; vp1 += 64;
  __syncthreads();

  int cur = 0;
  for (int jt = 0; jt < 16; ++jt) {
    if (jt < 15) {
      stage(cur ^ 1);
      kp0 += 65536; kp1 += 65536; vp0 += 64; vp1 += 64;
    }
    const char* kb = Kl + cur * 8192;
    const char* vb = Vl + cur * 8192;

    f32x4 sacc[2][4];
#pragma unroll
    for (int g = 0; g < 2; ++g)
#pragma unroll
      for (int ct = 0; ct < 4; ++ct) sacc[g][ct] = (f32x4){0.f, 0.f, 0.f, 0.f};

    __builtin_amdgcn_s_setprio(1);
#pragma unroll
    for (int ct = 0; ct < 4; ++ct) {
      const int R = r0 + ((ct & 1) << 2) + ((ct >> 1) << 5);
      const char* rp = kb + R * 128;
      s16x8 ka0 = *reinterpret_cast<const s16x8*>(rp + ((lk * 16) ^ swk));
      s16x8 ka1 = *reinterpret_cast<const s16x8*>(rp + ((64 + lk * 16) ^ swk));
      sacc[0][ct] = __builtin_amdgcn_mfma_f32_16x16x32_bf16(ka0, qf[0][0], sacc[0][ct], 0, 0, 0);
      sacc[0][ct] = __builtin_amdgcn_mfma_f32_16x16x32_bf16(ka1, qf[0][1], sacc[0][ct], 0, 0, 0);
      sacc[1][ct] = __builtin_amdgcn_mfma_f32_16x16x32_bf16(ka0, qf[1][0], sacc[1][ct], 0, 0, 0);
      sacc[1][ct] = __builtin_amdgcn_mfma_f32_16x16x32_bf16(ka1, qf[1][1], sacc[1][ct], 0, 0, 0);
    }
    __builtin_amdgcn_s_setprio(0);

#pragma unroll
    for (int g = 0; g < 2; ++g)
#pragma unroll
      for (int ct = 0; ct < 4; ++ct)
#pragma unroll
        for (int j = 0; j < 4; ++j)
          sacc[g][ct][j] = fexp2(sacc[g][ct][j]);

#pragma unroll
    for (int f = 0; f < 2; ++f) {
      s16x8 va[4];
#pragma unroll
      for (int dt = 0; dt < 4; ++dt)
        va[dt] = *reinterpret_cast<const s16x8*>(vb + (dt * 16 + l16) * 128 + ((f * 64 + lk * 16) ^ swv));
      s16x8 pf[2];
#pragma unroll
      for (int g = 0; g < 2; ++g) {
        const f32x4 pA = sacc[g][2 * f];
        const f32x4 pB = sacc[g][2 * f + 1];
        union { unsigned u[4]; s16x8 v; } pk;
        pk.u[0] = cvtpk(pA[0], pA[1]);
        pk.u[1] = cvtpk(pA[2], pA[3]);
        pk.u[2] = cvtpk(pB[0], pB[1]);
        pk.u[3] = cvtpk(pB[2], pB[3]);
        pf[g] = pk.v;
      }
      __builtin_amdgcn_s_setprio(1);
#pragma unroll
      for (int dt = 0; dt < 4; ++dt) {
        Oacc[0][dt] = __builtin_amdgcn_mfma_f32_16x16x32_bf16(va[dt], pf[0], Oacc[0][dt], 0, 0, 0);
        Oacc[1][dt] = __builtin_amdgcn_mfma_f32_16x16x32_bf16(va[dt], pf[1], Oacc[1][dt], 0, 0, 0);
      }
      Osum[0] = __builtin_amdgcn_mfma_f32_16x16x32_bf16(ones, pf[0], Osum[0], 0, 0, 0);
      Osum[1] = __builtin_amdgcn_mfma_f32_16x16x32_bf16(ones, pf[1], Osum[1], 0, 0, 0);
      __builtin_amdgcn_s_setprio(0);
    }
    __syncthreads();
    cur ^= 1;
  }

  if (w >= 4) {
    char* mb = smem + (((w - 4) * 64 + l) * 128);
#pragma unroll
    for (int g = 0; g < 2; ++g)
#pragma unroll
      for (int dt = 0; dt < 4; ++dt)
        *reinterpret_cast<f32x4*>(mb + (((g * 4 + dt) * 16) ^ ((l & 7) << 4))) = Oacc[g][dt];
    dmerge[((w - 4) * 64 + l) * 2 + 0] = Osum[0][0];
    dmerge[((w - 4) * 64 + l) * 2 + 1] = Osum[1][0];
  }
  __syncthreads();
  if (w < 4) {
    const char* mb = smem + ((w * 64 + l) * 128);
#pragma unroll
    for (int g = 0; g < 2; ++g) {
      float inv = 1.f / (Osum[g][0] + dmerge[(w * 64 + l) * 2 + g]);
      u16* op = Rb + ((size_t)(b * LQ_ + qrow0 + g * 16 + l16)) * 1024 + h * 64 + lk * 4;
#pragma unroll
      for (int dt = 0; dt < 4; ++dt) {
        f32x4 o2 = *reinterpret_cast<const f32x4*>(mb + (((g * 4 + dt) * 16) ^ ((l & 7) << 4)));
        f32x4 s = Oacc[g][dt] + o2;
        ushort4 o;
        o.x = f2b(s[0] * inv); o.y = f2b(s[1] * inv);
        o.z = f2b(s[2] * inv); o.w = f2b(s[3] * inv);
        *reinterpret_cast<ushort4*>(op + dt * 16) = o;
      }
    }
  }
}

// ---------------- launch ----------------
extern "C" void kernel_launch(void* const* d_in, const int* in_sizes, int n_in,
                              void* d_out, int out_size, void* d_ws, size_t ws_size,
                              hipStream_t stream) {
  const float* x   = (const float*)d_in[0];
  const float* y   = (const float*)d_in[1];
  const float* Wq  = (const float*)d_in[2];
  const float* Wkv = (const float*)d_in[3];
  const float* Wp  = (const float*)d_in[4];
  const float* bp  = (const float*)d_in[5];
  float* out = (float*)d_out;

  u16* p = (u16*)d_ws;
  u16* xb   = p; p += (size_t)4096 * 1024;
  u16* yb   = p; p += (size_t)4096 * 768;
  u16* WqT  = p; p += (size_t)1024 * 1024;
  u16* WkvT = p; p += (size_t)2048 * 768;
  u16* WpT  = p; p += (size_t)1024 * 1024;
  u16* Qb   = p; p += (size_t)4096 * 1024;
  u16* Kbf  = p; p += (size_t)4096 * 1024;   // K compact [b*2048+kv][h*64+d]
  u16* VTb  = p; p += (size_t)4096 * 1024;   // [32][64][2048]
  u16* Rb   = p; p += (size_t)4096 * 1024;

  prep<<<8064, 256, 0, stream>>>(x, xb, y, yb, Wq, WqT, Wkv, WkvT, Wp, WpT);

  // Q = (x @ Wq)*QSCALE and KV = y @ Wkv (K -> Kbf, V -> VTb transposed), one launch
  gemm_qkv<<<1536, 256, 0, stream>>>(xb, WqT, yb, WkvT, Qb, Kbf, VTb);
  // attention -> Rb [4096,1024] (halves merged in-block)
  flash_attn<<<512, 512, 0, stream>>>(Kbf, Qb, VTb, Rb);
  // out = Rb @ Wproj + bias : fp32 [4096,1024]
  gemm_proj<<<512, 256, 0, stream>>>(Rb, WpT, out, bp);
}